// Round 12
// baseline (67.165 us; speedup 1.0000x reference)
//
#include <hip/hip_runtime.h>
#include <math.h>

#define LQ 1024
#define DD 512
#define DK 64
#define RR 2

typedef unsigned short ushort_t;
typedef __attribute__((ext_vector_type(8))) _Float16 f16x8;
typedef __attribute__((ext_vector_type(4))) float f32x4;

__device__ inline ushort_t f16b(float x) {
    union { _Float16 h; ushort_t u; } c; c.h = (_Float16)x; return c.u;
}
__device__ inline float f16tof(ushort_t u) {
    union { ushort_t u; _Float16 h; } c; c.u = u; return (float)c.h;
}
__device__ inline uint4 pku(float4 a, float4 b) {
    uint4 v;
    v.x = (unsigned)f16b(a.x) | ((unsigned)f16b(a.y) << 16);
    v.y = (unsigned)f16b(a.z) | ((unsigned)f16b(a.w) << 16);
    v.z = (unsigned)f16b(b.x) | ((unsigned)f16b(b.y) << 16);
    v.w = (unsigned)f16b(b.z) | ((unsigned)f16b(b.w) << 16);
    return v;
}
__device__ inline f16x8 pk8(float4 a, float4 b) {
    f16x8 r;
    r[0] = (_Float16)a.x; r[1] = (_Float16)a.y; r[2] = (_Float16)a.z; r[3] = (_Float16)a.w;
    r[4] = (_Float16)b.x; r[5] = (_Float16)b.y; r[6] = (_Float16)b.z; r[7] = (_Float16)b.w;
    return r;
}

// ---------------- K1: projections + fused hash; on-the-fly weight transpose-convert ----------------
// blocks [0,256): Q both fp16-split passes + fused hash epilogue. [256,512): V single pass.
// B staging: thread owns a 4x4 block of W [k][n]; register transpose -> uint2 writes
// into fragment layout with swizzle f(c) = ((c>>2)^c)&7 (write & read consistent).
__global__ __launch_bounds__(256) void gemm_hash(const float* __restrict__ query,
                                                 const float* __restrict__ value,
                                                 const float* __restrict__ Wq,
                                                 const float* __restrict__ Wv,
                                                 const float* __restrict__ bq,
                                                 const float* __restrict__ bv,
                                                 const float* __restrict__ rnd,
                                                 float* __restrict__ Qf, float* __restrict__ Vf,
                                                 int* __restrict__ HASH, float* __restrict__ RNORM) {
    // per buffer (24576 B): Ah@0(4K) Am@4096(4K) Bh@8192(8K) Bm@16384(8K); 2 buffers
    // epilogue overlay: qtile[32][65]@0 (8320 B), rmn[64][64]@8320 (16384 B)
    __shared__ __align__(16) char SM[49152];
    const int tid = threadIdx.x;
    const int b = blockIdx.x;
    const bool isQ = (b < 256);
    const int t = isQ ? b : b - 256;
    const int m0 = (t >> 3) * 32, n0 = (t & 7) * 64;
    const int wave = tid >> 6, lane = tid & 63;
    const int wm_ = wave & 1, wn_ = wave >> 1;
    const int la = lane & 15, gq = lane >> 4;
    // A staging coords (row stride 128 B, oct^row swizzle) — unchanged from round 11
    const int arow = tid >> 3, aoct = tid & 7;
    const int abyte = arow * 128 + ((aoct ^ (arow & 7)) << 4);
    const size_t gA = (size_t)(m0 + arow) * DD + aoct * 8;
    // B staging coords: 4x4 transpose blocks
    const int kb4 = tid >> 4, nb4 = tid & 15;
    // fragment byte offsets
    const int farow = wm_ * 16 + la;
    int fA[2], fB[2][2];
#pragma unroll
    for (int p2 = 0; p2 < 2; ++p2)
        fA[p2] = farow * 128 + (((p2 * 4 + gq) ^ (farow & 7)) << 4);
#pragma unroll
    for (int j = 0; j < 2; ++j) {
        int c = wn_ * 32 + j * 16 + la;
        int fc = ((c >> 2) ^ c) & 7;
#pragma unroll
        for (int p2 = 0; p2 < 2; ++p2)
            fB[j][p2] = c * 128 + (((p2 * 4 + gq) ^ fc) << 4);
    }
    const float* Asrc = isQ ? query : value;
    const float* Wsrc = isQ ? Wq : Wv;
    const float* Wbase = Wsrc + (size_t)(kb4 * 4) * DD + n0 + nb4 * 4;
    f32x4 acc0[2] = {}, acc1[2] = {};
    float4 xa0 = *(const float4*)(Asrc + gA);
    float4 xa1 = *(const float4*)(Asrc + gA + 4);
    float4 wb0 = *(const float4*)(Wbase + (size_t)0 * DD);
    float4 wb1 = *(const float4*)(Wbase + (size_t)1 * DD);
    float4 wb2 = *(const float4*)(Wbase + (size_t)2 * DD);
    float4 wb3 = *(const float4*)(Wbase + (size_t)3 * DD);
    auto STAGE = [&](int pb) {
        char* base = SM + pb * 24576;
        // A plane(s)
        *(uint4*)(base + abyte) = pku(xa0, xa1);
        if (isQ) {
            float4 r0, r1;
            r0.x = (xa0.x - f16tof(f16b(xa0.x))) * 2048.f;
            r0.y = (xa0.y - f16tof(f16b(xa0.y))) * 2048.f;
            r0.z = (xa0.z - f16tof(f16b(xa0.z))) * 2048.f;
            r0.w = (xa0.w - f16tof(f16b(xa0.w))) * 2048.f;
            r1.x = (xa1.x - f16tof(f16b(xa1.x))) * 2048.f;
            r1.y = (xa1.y - f16tof(f16b(xa1.y))) * 2048.f;
            r1.z = (xa1.z - f16tof(f16b(xa1.z))) * 2048.f;
            r1.w = (xa1.w - f16tof(f16b(xa1.w))) * 2048.f;
            *(uint4*)(base + 4096 + abyte) = pku(r0, r1);
        }
        // B planes: register 4x4 transpose + convert (elementwise identical to prep_w)
        float wl[4][4];
        wl[0][0] = wb0.x; wl[0][1] = wb0.y; wl[0][2] = wb0.z; wl[0][3] = wb0.w;
        wl[1][0] = wb1.x; wl[1][1] = wb1.y; wl[1][2] = wb1.z; wl[1][3] = wb1.w;
        wl[2][0] = wb2.x; wl[2][1] = wb2.y; wl[2][2] = wb2.z; wl[2][3] = wb2.w;
        wl[3][0] = wb3.x; wl[3][1] = wb3.y; wl[3][2] = wb3.z; wl[3][3] = wb3.w;
#pragma unroll
        for (int j = 0; j < 4; ++j) {
            int c = nb4 * 4 + j;
            int fc = ((c >> 2) ^ c) & 7;
            int byteo = c * 128 + (((kb4 >> 1) ^ fc) << 4) + (kb4 & 1) * 8;
            ushort_t h4[4];
#pragma unroll
            for (int i = 0; i < 4; ++i) h4[i] = f16b(wl[i][j]);
            uint2 hv;
            hv.x = h4[0] | ((unsigned)h4[1] << 16);
            hv.y = h4[2] | ((unsigned)h4[3] << 16);
            *(uint2*)(base + 8192 + byteo) = hv;
            if (isQ) {
                ushort_t m4[4];
#pragma unroll
                for (int i = 0; i < 4; ++i)
                    m4[i] = f16b((wl[i][j] - f16tof(h4[i])) * 2048.f);
                uint2 mv;
                mv.x = m4[0] | ((unsigned)m4[1] << 16);
                mv.y = m4[2] | ((unsigned)m4[3] << 16);
                *(uint2*)(base + 16384 + byteo) = mv;
            }
        }
    };
    STAGE(0);
    int p = 0;
    for (int kt = 0; kt < DD; kt += 64) {
        __syncthreads();
        const bool more = (kt + 64 < DD);
        if (more) {
            xa0 = *(const float4*)(Asrc + gA + kt + 64);
            xa1 = *(const float4*)(Asrc + gA + kt + 68);
            wb0 = *(const float4*)(Wbase + (size_t)(kt + 64) * DD);
            wb1 = *(const float4*)(Wbase + (size_t)(kt + 65) * DD);
            wb2 = *(const float4*)(Wbase + (size_t)(kt + 66) * DD);
            wb3 = *(const float4*)(Wbase + (size_t)(kt + 67) * DD);
        }
        char* base = SM + p * 24576;
#pragma unroll
        for (int p2 = 0; p2 < 2; ++p2) {
            f16x8 ah = *(const f16x8*)(base + fA[p2]);
            f16x8 bh0 = *(const f16x8*)(base + 8192 + fB[0][p2]);
            f16x8 bh1 = *(const f16x8*)(base + 8192 + fB[1][p2]);
            acc0[0] = __builtin_amdgcn_mfma_f32_16x16x32_f16(ah, bh0, acc0[0], 0, 0, 0);
            acc0[1] = __builtin_amdgcn_mfma_f32_16x16x32_f16(ah, bh1, acc0[1], 0, 0, 0);
            if (isQ) {
                f16x8 am = *(const f16x8*)(base + 4096 + fA[p2]);
                f16x8 bm0 = *(const f16x8*)(base + 16384 + fB[0][p2]);
                f16x8 bm1 = *(const f16x8*)(base + 16384 + fB[1][p2]);
                acc1[0] = __builtin_amdgcn_mfma_f32_16x16x32_f16(ah, bm0, acc1[0], 0, 0, 0);
                acc1[0] = __builtin_amdgcn_mfma_f32_16x16x32_f16(am, bh0, acc1[0], 0, 0, 0);
                acc1[1] = __builtin_amdgcn_mfma_f32_16x16x32_f16(ah, bm1, acc1[1], 0, 0, 0);
                acc1[1] = __builtin_amdgcn_mfma_f32_16x16x32_f16(am, bh1, acc1[1], 0, 0, 0);
            }
        }
        if (more) STAGE(p ^ 1);
        p ^= 1;
    }
    __syncthreads();                             // all fragment reads done; LDS reusable
    if (!isQ) {
#pragma unroll
        for (int j = 0; j < 2; ++j) {
            int cl = wn_ * 32 + j * 16 + la;
            float bias_ = bv[n0 + cl];
#pragma unroll
            for (int reg = 0; reg < 4; ++reg) {
                int rl = wm_ * 16 + gq * 4 + reg;
                Vf[(size_t)n0 * LQ + (size_t)(m0 + rl) * DK + cl] = acc0[j][reg] + bias_;
            }
        }
        return;
    }
    // ---- Q epilogue: combine passes, store Qf, fused hash (bit-identical) ----
    float (*qtile)[65] = (float(*)[65])SM;
    float (*rmn)[64] = (float(*)[64])(SM + 8320);
#pragma unroll
    for (int j = 0; j < 2; ++j) {
        int cl = wn_ * 32 + j * 16 + la;
        float bq_ = bq[n0 + cl];
#pragma unroll
        for (int reg = 0; reg < 4; ++reg) {
            int rl = wm_ * 16 + gq * 4 + reg;
            float x = acc0[j][reg] + acc1[j][reg] * (1.f / 2048.f) + bq_;
            Qf[(size_t)n0 * LQ + (size_t)(m0 + rl) * DK + cl] = x;
            qtile[rl][cl] = x;
        }
    }
    for (int idx = tid; idx < 4096; idx += 256)
        rmn[idx >> 6][idx & 63] = rnd[idx];
    __syncthreads();
    if (tid < 128) {
        int d = tid >> 1, rh = tid & 1;
        float s = 0.f;
        for (int j = 0; j < 32; ++j) { float x = rmn[d][rh * 32 + j]; s += x * x; }
        float nrm = sqrtf(s);
        for (int j = 0; j < 32; ++j) rmn[d][rh * 32 + j] = rmn[d][rh * 32 + j] / nrm;
    }
    __syncthreads();
    const int j = lane & 31, r = lane >> 5;
    const int bh = n0 >> 6;
    for (int it = 0; it < 8; ++it) {
        const int rl = it * 4 + wave;
        const int row = (bh << 10) + m0 + rl;
        float x = qtile[rl][lane];
        float s2 = x * x;
#pragma unroll
        for (int m = 1; m < 64; m <<= 1) s2 += __shfl_xor(s2, m);
        if (lane == 0) RNORM[row] = 1.0f / sqrtf(s2);
        float p0 = 0.f, p1 = 0.f, p2 = 0.f, p3 = 0.f;
#pragma unroll 4
        for (int d = 0; d < 64; d += 4) {
            p0 += __shfl(x, d + 0) * rmn[d + 0][lane];
            p1 += __shfl(x, d + 1) * rmn[d + 1][lane];
            p2 += __shfl(x, d + 2) * rmn[d + 2][lane];
            p3 += __shfl(x, d + 3) * rmn[d + 3][lane];
        }
        float pr = (p0 + p1) + (p2 + p3);
        float bv_; int bi;
        if (pr >= -pr) { bv_ = pr; bi = j; } else { bv_ = -pr; bi = 32 + j; }
#pragma unroll
        for (int m = 1; m < 32; m <<= 1) {
            float ov = __shfl_xor(bv_, m);
            int oi = __shfl_xor(bi, m);
            if (ov > bv_ || (ov == bv_ && oi < bi)) { bv_ = ov; bi = oi; }
        }
        if (j == 0) HASH[((size_t)bh * RR + r) * LQ + m0 + rl] = bi;
    }
}

// ---------------- K2: stable counting sort per (bh, r) ----------------
__global__ __launch_bounds__(256) void sort_kernel(const int* __restrict__ HASH,
                                                   int* __restrict__ HIDX,
                                                   int* __restrict__ OIDX,
                                                   int* __restrict__ HSORT) {
    __shared__ __align__(16) char SM[39424];
    int* hl = (int*)SM;
    ushort_t (*cnt)[64] = (ushort_t(*)[64])(SM + 4096);
    int (*psum)[4] = (int(*)[4])(SM + 36864);
    int (*poff)[4] = (int(*)[4])(SM + 37888);
    int* base = (int*)(SM + 38912);
    const int tid = threadIdx.x;
    const int pair = blockIdx.x;
    const int* hsrc = HASH + (size_t)pair * LQ;
    for (int i = tid; i < 1024; i += 256) hl[i] = hsrc[i];
    int* cz = (int*)(SM + 4096);
    for (int i = tid; i < 8192; i += 256) cz[i] = 0;
    __syncthreads();
    for (int i = 0; i < 4; ++i) {
        int h = hl[tid * 4 + i];
        cnt[tid][h] += 1;
    }
    __syncthreads();
    {
        int h = tid >> 2, seg = tid & 3;
        int run = 0;
        for (int tt = seg * 64; tt < seg * 64 + 64; ++tt) {
            int tmp = cnt[tt][h];
            cnt[tt][h] = (ushort_t)run;
            run += tmp;
        }
        psum[h][seg] = run;
    }
    __syncthreads();
    if (tid < 64) {
        int run = 0;
#pragma unroll
        for (int seg = 0; seg < 4; ++seg) { int t = psum[tid][seg]; poff[tid][seg] = run; run += t; }
        int incl = run;
#pragma unroll
        for (int d = 1; d < 64; d <<= 1) {
            int y = __shfl_up(incl, d);
            if (tid >= d) incl += y;
        }
        base[tid] = incl - run;
    }
    __syncthreads();
    int* HI = HIDX + (size_t)pair * LQ;
    int* OI = OIDX + (size_t)pair * LQ;
    int* HS = HSORT + (size_t)pair * LQ;
    const int myseg = tid >> 6;
    for (int i = 0; i < 4; ++i) {
        int l = tid * 4 + i;
        int h = hl[l];
        int pos = base[h] + poff[h][myseg] + cnt[tid][h];
        cnt[tid][h] = (ushort_t)(cnt[tid][h] + 1);
        HI[pos] = l;
        OI[l] = pos;
        HS[pos] = h;
    }
}

// ---------------- K3: scores(MFMA fp16) + penalties(f32) + softmax partials + PV(MFMA fp16) ----
__global__ __launch_bounds__(256) void spv_kernel(const float* __restrict__ Q,
                                                  const float* __restrict__ RNORM,
                                                  const float* __restrict__ Vf,
                                                  const int* __restrict__ HIDX,
                                                  const int* __restrict__ OIDX,
                                                  const int* __restrict__ HSORT,
                                                  float* __restrict__ PV,
                                                  float2* __restrict__ ML) {
    const int n = blockIdx.x, r = blockIdx.y, bh = blockIdx.z;
    const int pair = bh * RR + r;
    __shared__ __align__(16) char SM[28800];
    float (*Vt)[68] = (float(*)[68])SM;
    float (*Pf)[68] = (float(*)[68])(SM + 17408);
    float (*redm)[4] = (float(*)[4])(SM + 26112);
    float (*redl)[4] = (float(*)[4])(SM + 26624);
    int* qi_l = (int*)(SM + 27136);
    int* hsq  = (int*)(SM + 27264);
    int* Aq   = (int*)(SM + 27392);
    int* ki_l = (int*)(SM + 27520);
    int* hsk  = (int*)(SM + 27776);
    int* Ak   = (int*)(SM + 28032);
    float* krn  = (float*)(SM + 28288);
    float* lcnt = (float*)(SM + 28544);
    const int tid = threadIdx.x;
    const int wave = tid >> 6, lane = tid & 63;
    const int la = lane & 15, gq = lane >> 4;
    const int* HI = HIDX + (size_t)pair * LQ;
    const int* OI = OIDX + (size_t)pair * LQ;
    const int* HS = HSORT + (size_t)pair * LQ;
    if (tid < 32) {
        int s = n * 32 + tid;
        qi_l[tid] = HI[s]; hsq[tid] = HS[s]; Aq[tid] = OI[s];
    } else if (tid < 96) {
        int k = tid - 32;
        int t = (n - 1) * 32 + k;
        if (t < 0) { ki_l[k] = -1; hsk[k] = 0; Ak[k] = 0; krn[k] = 0.f; }
        else {
            int ki = HI[t];
            ki_l[k] = ki; hsk[k] = HS[t]; Ak[k] = OI[t];
            krn[k] = RNORM[(size_t)bh * LQ + ki];
        }
    }
    __syncthreads();
    if (tid == 0) {
        if (n > 0) {
            for (int k = 0; k < 64; ++k) lcnt[k] = 0.f;
        } else {
            int zc = 0;
            for (int k = 32; k < 64; ++k) zc += (Ak[k] == 0);
            float l32 = logf((float)(32 + zc));
            for (int k = 0; k < 32; ++k) lcnt[k] = l32;
            for (int k = 32; k < 64; ++k) lcnt[k] = (Ak[k] == 0) ? l32 : 0.f;
        }
    }
    {
        int row = tid >> 3, o = tid & 7;
        const float* src = Q + ((size_t)bh * LQ + qi_l[row]) * DK + o * 8;
        float4 u0 = ((const float4*)src)[0];
        float4 u1 = ((const float4*)src)[1];
        int p = o >> 2, s = o & 3;
        int sw = (row & 3) ^ ((row >> 2) & 3);
        *(uint4*)(SM + p * 2048 + row * 64 + ((s ^ sw) << 4)) = pku(u0, u1);
    }
    {
        int row = tid >> 2, o2 = tid & 3;
        int ki = ki_l[row];
        float rn = krn[row];
        float4 u0 = {0,0,0,0}, u1 = {0,0,0,0}, u2 = {0,0,0,0}, u3 = {0,0,0,0};
        if (ki >= 0) {
            const float* src = Q + ((size_t)bh * LQ + ki) * DK + o2 * 16;
            u0 = ((const float4*)src)[0]; u1 = ((const float4*)src)[1];
            u2 = ((const float4*)src)[2]; u3 = ((const float4*)src)[3];
            u0.x *= rn; u0.y *= rn; u0.z *= rn; u0.w *= rn;
            u1.x *= rn; u1.y *= rn; u1.z *= rn; u1.w *= rn;
            u2.x *= rn; u2.y *= rn; u2.z *= rn; u2.w *= rn;
            u3.x *= rn; u3.y *= rn; u3.z *= rn; u3.w *= rn;
        }
        int p = o2 >> 1, sb = (o2 & 1) * 2;
        int sw = (row & 3) ^ ((row >> 2) & 3);
        *(uint4*)(SM + 4096 + p * 4096 + row * 64 + ((sb ^ sw) << 4)) = pku(u0, u1);
        *(uint4*)(SM + 4096 + p * 4096 + row * 64 + (((sb + 1) ^ sw) << 4)) = pku(u2, u3);
    }
    __syncthreads();
    f32x4 accS[2] = {};
    {
        int rb = wave * 16 + la;
        int swb = (rb & 3) ^ ((rb >> 2) & 3);
        f16x8 bk[2], aq[2][2];
#pragma unroll
        for (int p = 0; p < 2; ++p)
            bk[p] = *(const f16x8*)(SM + 4096 + p * 4096 + rb * 64 + (((gq) ^ swb) << 4));
#pragma unroll
        for (int mf = 0; mf < 2; ++mf) {
            int ra = mf * 16 + la;
            int swa = (ra & 3) ^ ((ra >> 2) & 3);
#pragma unroll
            for (int p = 0; p < 2; ++p)
                aq[mf][p] = *(const f16x8*)(SM + p * 2048 + ra * 64 + (((gq) ^ swa) << 4));
        }
#pragma unroll
        for (int p = 0; p < 2; ++p)
#pragma unroll
            for (int mf = 0; mf < 2; ++mf)
                accS[mf] = __builtin_amdgcn_mfma_f32_16x16x32_f16(aq[mf][p], bk[p], accS[mf], 0, 0, 0);
    }
    const int key = wave * 16 + la;
    const int hk = hsk[key], ak = Ak[key];
    const float lc = lcnt[key];
    float sv[2][4], pmax[2][4];
#pragma unroll
    for (int mf = 0; mf < 2; ++mf)
#pragma unroll
        for (int reg = 0; reg < 4; ++reg) {
            int row = mf * 16 + gq * 4 + reg;
            int hq = hsq[row], aqv = Aq[row];
            float v = accS[mf][reg] * 0.125f;
            v = v - ((n == 0 && wave < 2) ? 1e9f : 0.f);
            v = v - ((hq == hk) ? 0.f : 1e9f);
            v = v - ((aqv > ak) ? 0.f : 1e9f);
            v = v - ((aqv == ak) ? 1e5f : 0.f);
            v = v - lc;
            sv[mf][reg] = v;
            float pm = v;
#pragma unroll
            for (int m_ = 1; m_ < 16; m_ <<= 1) pm = fmaxf(pm, __shfl_xor(pm, m_));
            pmax[mf][reg] = pm;
        }
    if (la == 0) {
#pragma unroll
        for (int mf = 0; mf < 2; ++mf)
#pragma unroll
            for (int reg = 0; reg < 4; ++reg)
                redm[mf * 16 + gq * 4 + reg][wave] = pmax[mf][reg];
    }
    __syncthreads();
    for (int idx = tid; idx < 64 * 16; idx += 256) {
        int row = idx >> 4, c4 = idx & 15;
        int ki = ki_l[row];
        float4 v;
        if (ki < 0) { v.x = 0.f; v.y = 0.f; v.z = 0.f; v.w = 0.f; }
        else v = ((const float4*)(Vf + ((size_t)bh * LQ + ki) * DK))[c4];
        Vt[c4 * 4 + 0][row] = v.x; Vt[c4 * 4 + 1][row] = v.y;
        Vt[c4 * 4 + 2][row] = v.z; Vt[c4 * 4 + 3][row] = v.w;
    }
    float mrow[2][4], lsum[2][4];
#pragma unroll
    for (int mf = 0; mf < 2; ++mf)
#pragma unroll
        for (int reg = 0; reg < 4; ++reg) {
            int row = mf * 16 + gq * 4 + reg;
            float4 rm = *(const float4*)&redm[row][0];
            float m = fmaxf(fmaxf(rm.x, rm.y), fmaxf(rm.z, rm.w));
            mrow[mf][reg] = m;
            float e = expf(sv[mf][reg] - m);
            Pf[row][key] = e;
            float ps = e;
#pragma unroll
            for (int m_ = 1; m_ < 16; m_ <<= 1) ps += __shfl_xor(ps, m_);
            lsum[mf][reg] = ps;
        }
    if (la == 0) {
#pragma unroll
        for (int mf = 0; mf < 2; ++mf)
#pragma unroll
            for (int reg = 0; reg < 4; ++reg)
                redl[mf * 16 + gq * 4 + reg][wave] = lsum[mf][reg];
    }
    __syncthreads();
#pragma unroll
    for (int mf = 0; mf < 2; ++mf)
#pragma unroll
        for (int reg = 0; reg < 4; ++reg) {
            int row = mf * 16 + gq * 4 + reg;
            float4 rl = *(const float4*)&redl[row][0];
            lsum[mf][reg] = (rl.x + rl.y) + (rl.z + rl.w);
        }
    f32x4 accO[2] = {};
    {
        int dimr = wave * 16 + la;
        f16x8 bf2[2], af[2][2];
#pragma unroll
        for (int p = 0; p < 2; ++p) {
            const float* vsrc = &Vt[dimr][p * 32 + gq * 8];
            float4 b0 = *(const float4*)vsrc;
            float4 b1 = *(const float4*)(vsrc + 4);
            bf2[p] = pk8(b0, b1);
        }
#pragma unroll
        for (int mf = 0; mf < 2; ++mf) {
            int qrow = mf * 16 + la;
#pragma unroll
            for (int p = 0; p < 2; ++p) {
                const float* psrc = &Pf[qrow][p * 32 + gq * 8];
                float4 a0 = *(const float4*)psrc;
                float4 a1 = *(const float4*)(psrc + 4);
                af[mf][p] = pk8(a0, a1);
            }
        }
#pragma unroll
        for (int p = 0; p < 2; ++p)
#pragma unroll
            for (int mf = 0; mf < 2; ++mf)
                accO[mf] = __builtin_amdgcn_mfma_f32_16x16x32_f16(af[mf][p], bf2[p], accO[mf], 0, 0, 0);
    }
#pragma unroll
    for (int mf = 0; mf < 2; ++mf)
#pragma unroll
        for (int reg = 0; reg < 4; ++reg) {
            int row = mf * 16 + gq * 4 + reg;
            int srt = n * 32 + row;
            PV[(((size_t)pair * LQ + srt) << 6) + wave * 16 + la] = accO[mf][reg];
        }
    if (wave == 0 && la == 0) {
#pragma unroll
        for (int mf = 0; mf < 2; ++mf)
#pragma unroll
            for (int reg = 0; reg < 4; ++reg) {
                int row = mf * 16 + gq * 4 + reg;
                ML[(size_t)pair * LQ + n * 32 + row] = make_float2(mrow[mf][reg], lsum[mf][reg]);
            }
    }
}

// ---------------- K4: output projection, on-the-fly Wo convert, fused combine ----------------
__global__ __launch_bounds__(256) void out_combine(const float* __restrict__ PV,
                                                   const float2* __restrict__ ML,
                                                   const int* __restrict__ OIDX,
                                                   const float* __restrict__ Wo,
                                                   const float* __restrict__ bo,
                                                   float* __restrict__ out) {
    // per buffer (12288 B): Ah@0(4K) Bh@4096(8K); 2 buffers
    __shared__ __align__(16) char SM[24576];
    const int tid = threadIdx.x;
    const int b = blockIdx.x;
    const int m0 = (b >> 3) * 32, n0 = (b & 7) * 64;
    const int wave = tid >> 6, lane = tid & 63;
    const int wm_ = wave & 1, wn_ = wave >> 1;
    const int la = lane & 15, gq = lane >> 4;
    const int arow = tid >> 3, aoct = tid & 7;
    const int abyte = arow * 128 + ((aoct ^ (arow & 7)) << 4);
    const int kb4 = tid >> 4, nb4 = tid & 15;
    const float* Wbase = Wo + (size_t)(kb4 * 4) * DD + n0 + nb4 * 4;
    const int farow = wm_ * 16 + la;
    int fA[2], fB[2][2];
#pragma unroll
    for (int p2 = 0; p2 < 2; ++p2)
        fA[p2] = farow * 128 + (((p2 * 4 + gq) ^ (farow & 7)) << 4);
#pragma unroll
    for (int j = 0; j < 2; ++j) {
        int c = wn_ * 32 + j * 16 + la;
        int fc = ((c >> 2) ^ c) & 7;
#pragma unroll
        for (int p2 = 0; p2 < 2; ++p2)
            fB[j][p2] = c * 128 + (((p2 * 4 + gq) ^ fc) << 4);
    }
    const int l = m0 + arow;
    float4 a00, a01, a10, a11; float2 ml0, ml1;
    auto FETCH = [&](int h) {
        size_t p0 = (size_t)h * RR, p1 = p0 + 1;
        int s0 = OIDX[p0 * LQ + l], s1 = OIDX[p1 * LQ + l];
        ml0 = ML[p0 * LQ + s0]; ml1 = ML[p1 * LQ + s1];
        const float* q0 = PV + ((p0 * LQ + s0) << 6) + aoct * 8;
        const float* q1 = PV + ((p1 * LQ + s1) << 6) + aoct * 8;
        a00 = ((const float4*)q0)[0]; a01 = ((const float4*)q0)[1];
        a10 = ((const float4*)q1)[0]; a11 = ((const float4*)q1)[1];
    };
    float4 wb0 = *(const float4*)(Wbase + (size_t)0 * DD);
    float4 wb1 = *(const float4*)(Wbase + (size_t)1 * DD);
    float4 wb2 = *(const float4*)(Wbase + (size_t)2 * DD);
    float4 wb3 = *(const float4*)(Wbase + (size_t)3 * DD);
    FETCH(0);
    auto STAGE = [&](int pb) {
        char* base = SM + pb * 12288;
        float M = fmaxf(ml0.x, ml1.x);
        float w0 = expf(ml0.x - M);
        float w1 = expf(ml1.x - M);
        float denom = w0 * ml0.y + w1 * ml1.y;
        float4 c0, c1;
        c0.x = (w0 * a00.x + w1 * a10.x) / denom;
        c0.y = (w0 * a00.y + w1 * a10.y) / denom;
        c0.z = (w0 * a00.z + w1 * a10.z) / denom;
        c0.w = (w0 * a00.w + w1 * a10.w) / denom;
        c1.x = (w0 * a01.x + w1 * a11.x) / denom;
        c1.y = (w0 * a01.y + w1 * a11.y) / denom;
        c1.z = (w0 * a01.z + w1 * a11.z) / denom;
        c1.w = (w0 * a01.w + w1 * a11.w) / denom;
        *(uint4*)(base + abyte) = pku(c0, c1);
        float wl[4][4];
        wl[0][0] = wb0.x; wl[0][1] = wb0.y; wl[0][2] = wb0.z; wl[0][3] = wb0.w;
        wl[1][0] = wb1.x; wl[1][1] = wb1.y; wl[1][2] = wb1.z; wl[1][3] = wb1.w;
        wl[2][0] = wb2.x; wl[2][1] = wb2.y; wl[2][2] = wb2.z; wl[2][3] = wb2.w;
        wl[3][0] = wb3.x; wl[3][1] = wb3.y; wl[3][2] = wb3.z; wl[3][3] = wb3.w;
#pragma unroll
        for (int j = 0; j < 4; ++j) {
            int c = nb4 * 4 + j;
            int fc = ((c >> 2) ^ c) & 7;
            int byteo = c * 128 + (((kb4 >> 1) ^ fc) << 4) + (kb4 & 1) * 8;
            ushort_t h4[4];
#pragma unroll
            for (int i = 0; i < 4; ++i) h4[i] = f16b(wl[i][j]);
            uint2 hv;
            hv.x = h4[0] | ((unsigned)h4[1] << 16);
            hv.y = h4[2] | ((unsigned)h4[3] << 16);
            *(uint2*)(base + 4096 + byteo) = hv;
        }
    };
    STAGE(0);
    f32x4 acc[2] = {};
    int p = 0;
    for (int kt = 0; kt < DD; kt += 64) {
        __syncthreads();
        const bool more = (kt + 64 < DD);
        if (more) {
            FETCH((kt + 64) >> 6);
            wb0 = *(const float4*)(Wbase + (size_t)(kt + 64) * DD);
            wb1 = *(const float4*)(Wbase + (size_t)(kt + 65) * DD);
            wb2 = *(const float4*)(Wbase + (size_t)(kt + 66) * DD);
            wb3 = *(const float4*)(Wbase + (size_t)(kt + 67) * DD);
        }
        char* base = SM + p * 12288;
#pragma unroll
        for (int p2 = 0; p2 < 2; ++p2) {
            f16x8 ah = *(const f16x8*)(base + fA[p2]);
            f16x8 bh0 = *(const f16x8*)(base + 4096 + fB[0][p2]);
            f16x8 bh1 = *(const f16x8*)(base + 4096 + fB[1][p2]);
            acc[0] = __builtin_amdgcn_mfma_f32_16x16x32_f16(ah, bh0, acc[0], 0, 0, 0);
            acc[1] = __builtin_amdgcn_mfma_f32_16x16x32_f16(ah, bh1, acc[1], 0, 0, 0);
        }
        if (more) STAGE(p ^ 1);
        p ^= 1;
    }
#pragma unroll
    for (int j = 0; j < 2; ++j) {
        int cl = wn_ * 32 + j * 16 + la;
        float bb_ = bo[n0 + cl];
#pragma unroll
        for (int reg = 0; reg < 4; ++reg) {
            int rl = wm_ * 16 + gq * 4 + reg;
            out[(size_t)(m0 + rl) * DD + n0 + cl] = acc[j][reg] + bb_;
        }
    }
}

extern "C" void kernel_launch(void* const* d_in, const int* in_sizes, int n_in,
                              void* d_out, int out_size, void* d_ws, size_t ws_size,
                              hipStream_t stream) {
    const float* query = (const float*)d_in[0];
    const float* value = (const float*)d_in[2];
    const float* Wq = (const float*)d_in[4];
    const float* bq = (const float*)d_in[5];
    const float* Wv = (const float*)d_in[6];
    const float* bv = (const float*)d_in[7];
    const float* Wo = (const float*)d_in[8];
    const float* bo = (const float*)d_in[9];
    const float* rnd = (const float*)d_in[10];

    char* ws = (char*)d_ws;
    const size_t MB1 = 1u << 20;
    float*    Qf    = (float*)(ws);                       // [0,2MB)
    float*    Vf    = (float*)(ws + 2 * MB1);             // [2,4MB)
    float*    PV    = (float*)(ws + 4 * MB1);             // [4,8MB)
    float*    RNORM = (float*)(ws + 10 * MB1);            // 32KB
    char*     tail  = ws + 10 * MB1 + (64u << 10);
    int* HASH  = (int*)(tail);
    int* HIDX  = (int*)(tail + (64u << 10));
    int* OIDX  = (int*)(tail + (128u << 10));
    int* HSORT = (int*)(tail + (192u << 10));
    float2* ML = (float2*)(tail + (256u << 10));          // 128KB
    float* OUT = (float*)d_out;

    gemm_hash<<<512, 256, 0, stream>>>(query, value, Wq, Wv, bq, bv, rnd,
                                       Qf, Vf, HASH, RNORM);
    sort_kernel<<<16, 256, 0, stream>>>(HASH, HIDX, OIDX, HSORT);
    spv_kernel<<<dim3(32, 2, 8), 256, 0, stream>>>(Qf, RNORM, Vf, HIDX, OIDX, HSORT, PV, ML);
    out_combine<<<256, 256, 0, stream>>>(PV, ML, OIDX, Wo, bo, OUT);
}

// Round 13
// 65.949 us; speedup vs baseline: 1.0184x; 1.0184x over previous
//
#include <hip/hip_runtime.h>
#include <math.h>

#define LQ 1024
#define DD 512
#define DK 64
#define RR 2

typedef unsigned short ushort_t;
typedef __attribute__((ext_vector_type(8))) _Float16 f16x8;
typedef __attribute__((ext_vector_type(4))) float f32x4;

__device__ inline ushort_t f16b(float x) {
    union { _Float16 h; ushort_t u; } c; c.h = (_Float16)x; return c.u;
}
__device__ inline float f16tof(ushort_t u) {
    union { ushort_t u; _Float16 h; } c; c.u = u; return (float)c.h;
}
__device__ inline void store4u(ushort_t* p, const ushort_t h[4]) {
    uint2 v;
    v.x = h[0] | ((unsigned int)h[1] << 16); v.y = h[2] | ((unsigned int)h[3] << 16);
    *(uint2*)p = v;
}
__device__ inline uint4 pku(float4 a, float4 b) {
    uint4 v;
    v.x = (unsigned)f16b(a.x) | ((unsigned)f16b(a.y) << 16);
    v.y = (unsigned)f16b(a.z) | ((unsigned)f16b(a.w) << 16);
    v.z = (unsigned)f16b(b.x) | ((unsigned)f16b(b.y) << 16);
    v.w = (unsigned)f16b(b.z) | ((unsigned)f16b(b.w) << 16);
    return v;
}
__device__ inline f16x8 pk8(float4 a, float4 b) {
    f16x8 r;
    r[0] = (_Float16)a.x; r[1] = (_Float16)a.y; r[2] = (_Float16)a.z; r[3] = (_Float16)a.w;
    r[4] = (_Float16)b.x; r[5] = (_Float16)b.y; r[6] = (_Float16)b.z; r[7] = (_Float16)b.w;
    return r;
}

// ---------------- K0: weight transposes (Wq 2-level fp16, Wv/Wo 1-level fp16) ----------------
__global__ __launch_bounds__(256) void prep_w(const float* __restrict__ Wq,
                                              const float* __restrict__ Wv,
                                              const float* __restrict__ Wo,
                                              ushort_t* __restrict__ WqTh, ushort_t* __restrict__ WqTm,
                                              ushort_t* __restrict__ WvTh, ushort_t* __restrict__ WoTh) {
    __shared__ float tl[32][33];
    const int tid = threadIdx.x;
    const int b = blockIdx.x;
    const int mat = b >> 8;                // 0 Wq, 1 Wv, 2 Wo
    const int tile = b & 255;
    const int r0 = (tile >> 4) * 32;       // k rows
    const int c0 = (tile & 15) * 32;       // n cols
    const float* W = (mat == 0) ? Wq : ((mat == 1) ? Wv : Wo);
    const int rr = tid >> 3, cc = (tid & 7) * 4;
    *(float4*)&tl[rr][cc] = *(const float4*)(W + (size_t)(r0 + rr) * DD + c0 + cc);
    __syncthreads();
    float y[4];
#pragma unroll
    for (int i = 0; i < 4; ++i) y[i] = tl[cc + i][rr];
    size_t ob = (size_t)(c0 + rr) * DD + r0 + cc;
    if (mat == 0) {
        ushort_t h[4], m[4];
#pragma unroll
        for (int i = 0; i < 4; ++i) {
            h[i] = f16b(y[i]);
            m[i] = f16b((y[i] - f16tof(h[i])) * 2048.f);
        }
        store4u(WqTh + ob, h); store4u(WqTm + ob, m);
    } else {
        ushort_t h[4];
#pragma unroll
        for (int i = 0; i < 4; ++i) h[i] = f16b(y[i]);
        store4u((mat == 1 ? WvTh : WoTh) + ob, h);
    }
}

// ---------------- K1: projections + fused hash; BK=64, double-buffered LDS (round-11) ----------------
__global__ __launch_bounds__(256) void gemm_hash(const float* __restrict__ query,
                                                 const float* __restrict__ value,
                                                 const ushort_t* __restrict__ WqTh,
                                                 const ushort_t* __restrict__ WqTm,
                                                 const ushort_t* __restrict__ WvTh,
                                                 const float* __restrict__ bq,
                                                 const float* __restrict__ bv,
                                                 const float* __restrict__ rnd,
                                                 float* __restrict__ Qf, float* __restrict__ Vf,
                                                 int* __restrict__ HASH, float* __restrict__ RNORM) {
    __shared__ __align__(16) char SM[49152];
    const int tid = threadIdx.x;
    const int b = blockIdx.x;
    const bool isQ = (b < 256);
    const int t = isQ ? b : b - 256;
    const int m0 = (t >> 3) * 32, n0 = (t & 7) * 64;
    const int wave = tid >> 6, lane = tid & 63;
    const int wm_ = wave & 1, wn_ = wave >> 1;
    const int la = lane & 15, gq = lane >> 4;
    const int arow = tid >> 3, aoct = tid & 7;
    const int abyte = arow * 128 + ((aoct ^ (arow & 7)) << 4);
    const int brow = tid >> 2, bslot = (tid & 3) * 2;
    const int bbyte0 = brow * 128 + ((bslot ^ (brow & 7)) << 4);
    const int bbyte1 = brow * 128 + (((bslot + 1) ^ (brow & 7)) << 4);
    const size_t gA = (size_t)(m0 + arow) * DD + aoct * 8;
    const size_t gB = (size_t)(n0 + brow) * DD + bslot * 8;
    const int farow = wm_ * 16 + la;
    int fA[2], fB[2][2];
#pragma unroll
    for (int p2 = 0; p2 < 2; ++p2)
        fA[p2] = farow * 128 + (((p2 * 4 + gq) ^ (farow & 7)) << 4);
#pragma unroll
    for (int j = 0; j < 2; ++j) {
        int c = wn_ * 32 + j * 16 + la;
#pragma unroll
        for (int p2 = 0; p2 < 2; ++p2)
            fB[j][p2] = c * 128 + (((p2 * 4 + gq) ^ (c & 7)) << 4);
    }
    const float* Asrc = isQ ? query : value;
    const ushort_t* Bh_src = isQ ? WqTh : WvTh;
    f32x4 acc0[2] = {}, acc1[2] = {};
    float4 xa0 = *(const float4*)(Asrc + gA);
    float4 xa1 = *(const float4*)(Asrc + gA + 4);
    uint4 wh0 = *(const uint4*)(Bh_src + gB);
    uint4 wh1 = *(const uint4*)(Bh_src + gB + 8);
    uint4 wm0 = {}, wm1 = {};
    if (isQ) { wm0 = *(const uint4*)(WqTm + gB); wm1 = *(const uint4*)(WqTm + gB + 8); }
    auto STAGE = [&](int pb) {
        char* base = SM + pb * 24576;
        *(uint4*)(base + abyte) = pku(xa0, xa1);
        if (isQ) {
            float4 r0, r1;
            r0.x = (xa0.x - f16tof(f16b(xa0.x))) * 2048.f;
            r0.y = (xa0.y - f16tof(f16b(xa0.y))) * 2048.f;
            r0.z = (xa0.z - f16tof(f16b(xa0.z))) * 2048.f;
            r0.w = (xa0.w - f16tof(f16b(xa0.w))) * 2048.f;
            r1.x = (xa1.x - f16tof(f16b(xa1.x))) * 2048.f;
            r1.y = (xa1.y - f16tof(f16b(xa1.y))) * 2048.f;
            r1.z = (xa1.z - f16tof(f16b(xa1.z))) * 2048.f;
            r1.w = (xa1.w - f16tof(f16b(xa1.w))) * 2048.f;
            *(uint4*)(base + 4096 + abyte) = pku(r0, r1);
        }
        *(uint4*)(base + 8192 + bbyte0) = wh0;
        *(uint4*)(base + 8192 + bbyte1) = wh1;
        if (isQ) {
            *(uint4*)(base + 16384 + bbyte0) = wm0;
            *(uint4*)(base + 16384 + bbyte1) = wm1;
        }
    };
    STAGE(0);
    int p = 0;
    for (int kt = 0; kt < DD; kt += 64) {
        __syncthreads();
        const bool more = (kt + 64 < DD);
        if (more) {
            xa0 = *(const float4*)(Asrc + gA + kt + 64);
            xa1 = *(const float4*)(Asrc + gA + kt + 68);
            wh0 = *(const uint4*)(Bh_src + gB + kt + 64);
            wh1 = *(const uint4*)(Bh_src + gB + kt + 72);
            if (isQ) {
                wm0 = *(const uint4*)(WqTm + gB + kt + 64);
                wm1 = *(const uint4*)(WqTm + gB + kt + 72);
            }
        }
        char* base = SM + p * 24576;
#pragma unroll
        for (int p2 = 0; p2 < 2; ++p2) {
            f16x8 ah = *(const f16x8*)(base + fA[p2]);
            f16x8 bh0 = *(const f16x8*)(base + 8192 + fB[0][p2]);
            f16x8 bh1 = *(const f16x8*)(base + 8192 + fB[1][p2]);
            acc0[0] = __builtin_amdgcn_mfma_f32_16x16x32_f16(ah, bh0, acc0[0], 0, 0, 0);
            acc0[1] = __builtin_amdgcn_mfma_f32_16x16x32_f16(ah, bh1, acc0[1], 0, 0, 0);
            if (isQ) {
                f16x8 am = *(const f16x8*)(base + 4096 + fA[p2]);
                f16x8 bm0 = *(const f16x8*)(base + 16384 + fB[0][p2]);
                f16x8 bm1 = *(const f16x8*)(base + 16384 + fB[1][p2]);
                acc1[0] = __builtin_amdgcn_mfma_f32_16x16x32_f16(ah, bm0, acc1[0], 0, 0, 0);
                acc1[0] = __builtin_amdgcn_mfma_f32_16x16x32_f16(am, bh0, acc1[0], 0, 0, 0);
                acc1[1] = __builtin_amdgcn_mfma_f32_16x16x32_f16(ah, bm1, acc1[1], 0, 0, 0);
                acc1[1] = __builtin_amdgcn_mfma_f32_16x16x32_f16(am, bh1, acc1[1], 0, 0, 0);
            }
        }
        if (more) STAGE(p ^ 1);
        p ^= 1;
    }
    __syncthreads();
    if (!isQ) {
#pragma unroll
        for (int j = 0; j < 2; ++j) {
            int cl = wn_ * 32 + j * 16 + la;
            float bias_ = bv[n0 + cl];
#pragma unroll
            for (int reg = 0; reg < 4; ++reg) {
                int rl = wm_ * 16 + gq * 4 + reg;
                Vf[(size_t)n0 * LQ + (size_t)(m0 + rl) * DK + cl] = acc0[j][reg] + bias_;
            }
        }
        return;
    }
    float (*qtile)[65] = (float(*)[65])SM;
    float (*rmn)[64] = (float(*)[64])(SM + 8320);
#pragma unroll
    for (int j = 0; j < 2; ++j) {
        int cl = wn_ * 32 + j * 16 + la;
        float bq_ = bq[n0 + cl];
#pragma unroll
        for (int reg = 0; reg < 4; ++reg) {
            int rl = wm_ * 16 + gq * 4 + reg;
            float x = acc0[j][reg] + acc1[j][reg] * (1.f / 2048.f) + bq_;
            Qf[(size_t)n0 * LQ + (size_t)(m0 + rl) * DK + cl] = x;
            qtile[rl][cl] = x;
        }
    }
    for (int idx = tid; idx < 4096; idx += 256)
        rmn[idx >> 6][idx & 63] = rnd[idx];
    __syncthreads();
    if (tid < 128) {
        int d = tid >> 1, rh = tid & 1;
        float s = 0.f;
        for (int j = 0; j < 32; ++j) { float x = rmn[d][rh * 32 + j]; s += x * x; }
        float nrm = sqrtf(s);
        for (int j = 0; j < 32; ++j) rmn[d][rh * 32 + j] = rmn[d][rh * 32 + j] / nrm;
    }
    __syncthreads();
    const int j = lane & 31, r = lane >> 5;
    const int bh = n0 >> 6;
    for (int it = 0; it < 8; ++it) {
        const int rl = it * 4 + wave;
        const int row = (bh << 10) + m0 + rl;
        float x = qtile[rl][lane];
        float s2 = x * x;
#pragma unroll
        for (int m = 1; m < 64; m <<= 1) s2 += __shfl_xor(s2, m);
        if (lane == 0) RNORM[row] = 1.0f / sqrtf(s2);
        float p0 = 0.f, p1 = 0.f, p2 = 0.f, p3 = 0.f;
#pragma unroll 4
        for (int d = 0; d < 64; d += 4) {
            p0 += __shfl(x, d + 0) * rmn[d + 0][lane];
            p1 += __shfl(x, d + 1) * rmn[d + 1][lane];
            p2 += __shfl(x, d + 2) * rmn[d + 2][lane];
            p3 += __shfl(x, d + 3) * rmn[d + 3][lane];
        }
        float pr = (p0 + p1) + (p2 + p3);
        float bv_; int bi;
        if (pr >= -pr) { bv_ = pr; bi = j; } else { bv_ = -pr; bi = 32 + j; }
#pragma unroll
        for (int m = 1; m < 32; m <<= 1) {
            float ov = __shfl_xor(bv_, m);
            int oi = __shfl_xor(bi, m);
            if (ov > bv_ || (ov == bv_ && oi < bi)) { bv_ = ov; bi = oi; }
        }
        if (j == 0) HASH[((size_t)bh * RR + r) * LQ + m0 + rl] = bi;
    }
}

// ---------------- K2: fused per-pair counting sort + scores + softmax + PV ----------------
// Each block redundantly sorts its own pair from HASH (identical algorithm to the old
// sort_kernel), writes global OIDX (for out_combine), keeps HIl/HSl/OIl in LDS (u16),
// then runs the round-11 spv body using the LDS sort results.
__global__ __launch_bounds__(256) void spv_sort(const float* __restrict__ Q,
                                                const float* __restrict__ RNORM,
                                                const float* __restrict__ Vf,
                                                const int* __restrict__ HASH,
                                                int* __restrict__ OIDX,
                                                float* __restrict__ PV,
                                                float2* __restrict__ ML) {
    const int n = blockIdx.x, r = blockIdx.y, bh = blockIdx.z;
    const int pair = bh * RR + r;
    __shared__ __align__(16) char SM[45312];
    // spv regions
    float (*Vt)[68] = (float(*)[68])SM;
    float (*Pf)[68] = (float(*)[68])(SM + 17408);
    float (*redm)[4] = (float(*)[4])(SM + 26112);
    float (*redl)[4] = (float(*)[4])(SM + 26624);
    int* qi_l = (int*)(SM + 27136);
    int* hsq  = (int*)(SM + 27264);
    int* Aq   = (int*)(SM + 27392);
    int* ki_l = (int*)(SM + 27520);
    int* hsk  = (int*)(SM + 27776);
    int* Ak   = (int*)(SM + 28032);
    float* krn  = (float*)(SM + 28288);
    float* lcnt = (float*)(SM + 28544);
    // sort temps (overlay Vt/Pf — dead during sort; reused after)
    int* hl = (int*)SM;                                    // 4096 B @0
    ushort_t (*cnt)[64] = (ushort_t(*)[64])(SM + 4096);    // 32768 B
    int (*psum)[4] = (int(*)[4])(SM + 36864);              // 1024 B
    int (*poff)[4] = (int(*)[4])(SM + 37888);              // 1024 B
    int* sbase = (int*)(SM + 38912);                       // 256 B
    // sort results (persist through spv phase)
    ushort_t* HIl = (ushort_t*)(SM + 39168);               // 2048 B
    ushort_t* HSl = (ushort_t*)(SM + 41216);               // 2048 B
    ushort_t* OIl = (ushort_t*)(SM + 43264);               // 2048 B
    const int tid = threadIdx.x;
    const int wave = tid >> 6, lane = tid & 63;
    const int la = lane & 15, gq = lane >> 4;
    // ---- counting sort (bit-identical algorithm) ----
    {
        const int* hsrc = HASH + (size_t)pair * LQ;
        for (int i = tid; i < 1024; i += 256) hl[i] = hsrc[i];
        int* cz = (int*)(SM + 4096);
        for (int i = tid; i < 8192; i += 256) cz[i] = 0;
        __syncthreads();
        for (int i = 0; i < 4; ++i) {
            int h = hl[tid * 4 + i];
            cnt[tid][h] += 1;
        }
        __syncthreads();
        {
            int h = tid >> 2, seg = tid & 3;
            int run = 0;
            for (int tt = seg * 64; tt < seg * 64 + 64; ++tt) {
                int tmp = cnt[tt][h];
                cnt[tt][h] = (ushort_t)run;
                run += tmp;
            }
            psum[h][seg] = run;
        }
        __syncthreads();
        if (tid < 64) {
            int run = 0;
#pragma unroll
            for (int seg = 0; seg < 4; ++seg) { int t2 = psum[tid][seg]; poff[tid][seg] = run; run += t2; }
            int incl = run;
#pragma unroll
            for (int d = 1; d < 64; d <<= 1) {
                int y = __shfl_up(incl, d);
                if (tid >= d) incl += y;
            }
            sbase[tid] = incl - run;
        }
        __syncthreads();
        int* OIg = OIDX + (size_t)pair * LQ;
        const int myseg = tid >> 6;
        for (int i = 0; i < 4; ++i) {
            int l = tid * 4 + i;
            int h = hl[l];
            int pos = sbase[h] + poff[h][myseg] + cnt[tid][h];
            cnt[tid][h] = (ushort_t)(cnt[tid][h] + 1);
            HIl[pos] = (ushort_t)l;
            OIl[l] = (ushort_t)pos;
            HSl[pos] = (ushort_t)h;
            OIg[l] = pos;                 // redundant identical write across the pair's 32 blocks
        }
        __syncthreads();
    }
    // ---- meta extraction from LDS sort results ----
    if (tid < 32) {
        int s = n * 32 + tid;
        qi_l[tid] = HIl[s]; hsq[tid] = HSl[s]; Aq[tid] = OIl[s];
    } else if (tid < 96) {
        int k = tid - 32;
        int t2 = (n - 1) * 32 + k;
        if (t2 < 0) { ki_l[k] = -1; hsk[k] = 0; Ak[k] = 0; krn[k] = 0.f; }
        else {
            int ki = HIl[t2];
            ki_l[k] = ki; hsk[k] = HSl[t2]; Ak[k] = OIl[t2];
            krn[k] = RNORM[(size_t)bh * LQ + ki];
        }
    }
    __syncthreads();
    if (tid == 0) {
        if (n > 0) {
            for (int k = 0; k < 64; ++k) lcnt[k] = 0.f;
        } else {
            int zc = 0;
            for (int k = 32; k < 64; ++k) zc += (Ak[k] == 0);
            float l32 = logf((float)(32 + zc));
            for (int k = 0; k < 32; ++k) lcnt[k] = l32;
            for (int k = 32; k < 64; ++k) lcnt[k] = (Ak[k] == 0) ? l32 : 0.f;
        }
    }
    {
        int row = tid >> 3, o = tid & 7;
        const float* src = Q + ((size_t)bh * LQ + qi_l[row]) * DK + o * 8;
        float4 u0 = ((const float4*)src)[0];
        float4 u1 = ((const float4*)src)[1];
        int p = o >> 2, s = o & 3;
        int sw = (row & 3) ^ ((row >> 2) & 3);
        *(uint4*)(SM + p * 2048 + row * 64 + ((s ^ sw) << 4)) = pku(u0, u1);
    }
    {
        int row = tid >> 2, o2 = tid & 3;
        int ki = ki_l[row];
        float rn = krn[row];
        float4 u0 = {0,0,0,0}, u1 = {0,0,0,0}, u2 = {0,0,0,0}, u3 = {0,0,0,0};
        if (ki >= 0) {
            const float* src = Q + ((size_t)bh * LQ + ki) * DK + o2 * 16;
            u0 = ((const float4*)src)[0]; u1 = ((const float4*)src)[1];
            u2 = ((const float4*)src)[2]; u3 = ((const float4*)src)[3];
            u0.x *= rn; u0.y *= rn; u0.z *= rn; u0.w *= rn;
            u1.x *= rn; u1.y *= rn; u1.z *= rn; u1.w *= rn;
            u2.x *= rn; u2.y *= rn; u2.z *= rn; u2.w *= rn;
            u3.x *= rn; u3.y *= rn; u3.z *= rn; u3.w *= rn;
        }
        int p = o2 >> 1, sb = (o2 & 1) * 2;
        int sw = (row & 3) ^ ((row >> 2) & 3);
        *(uint4*)(SM + 4096 + p * 4096 + row * 64 + ((sb ^ sw) << 4)) = pku(u0, u1);
        *(uint4*)(SM + 4096 + p * 4096 + row * 64 + (((sb + 1) ^ sw) << 4)) = pku(u2, u3);
    }
    __syncthreads();
    f32x4 accS[2] = {};
    {
        int rb = wave * 16 + la;
        int swb = (rb & 3) ^ ((rb >> 2) & 3);
        f16x8 bk[2], aq[2][2];
#pragma unroll
        for (int p = 0; p < 2; ++p)
            bk[p] = *(const f16x8*)(SM + 4096 + p * 4096 + rb * 64 + (((gq) ^ swb) << 4));
#pragma unroll
        for (int mf = 0; mf < 2; ++mf) {
            int ra = mf * 16 + la;
            int swa = (ra & 3) ^ ((ra >> 2) & 3);
#pragma unroll
            for (int p = 0; p < 2; ++p)
                aq[mf][p] = *(const f16x8*)(SM + p * 2048 + ra * 64 + (((gq) ^ swa) << 4));
        }
#pragma unroll
        for (int p = 0; p < 2; ++p)
#pragma unroll
            for (int mf = 0; mf < 2; ++mf)
                accS[mf] = __builtin_amdgcn_mfma_f32_16x16x32_f16(aq[mf][p], bk[p], accS[mf], 0, 0, 0);
    }
    const int key = wave * 16 + la;
    const int hk = hsk[key], ak = Ak[key];
    const float lc = lcnt[key];
    float sv[2][4], pmax[2][4];
#pragma unroll
    for (int mf = 0; mf < 2; ++mf)
#pragma unroll
        for (int reg = 0; reg < 4; ++reg) {
            int row = mf * 16 + gq * 4 + reg;
            int hq = hsq[row], aqv = Aq[row];
            float v = accS[mf][reg] * 0.125f;
            v = v - ((n == 0 && wave < 2) ? 1e9f : 0.f);
            v = v - ((hq == hk) ? 0.f : 1e9f);
            v = v - ((aqv > ak) ? 0.f : 1e9f);
            v = v - ((aqv == ak) ? 1e5f : 0.f);
            v = v - lc;
            sv[mf][reg] = v;
            float pm = v;
#pragma unroll
            for (int m_ = 1; m_ < 16; m_ <<= 1) pm = fmaxf(pm, __shfl_xor(pm, m_));
            pmax[mf][reg] = pm;
        }
    if (la == 0) {
#pragma unroll
        for (int mf = 0; mf < 2; ++mf)
#pragma unroll
            for (int reg = 0; reg < 4; ++reg)
                redm[mf * 16 + gq * 4 + reg][wave] = pmax[mf][reg];
    }
    __syncthreads();
    for (int idx = tid; idx < 64 * 16; idx += 256) {
        int row = idx >> 4, c4 = idx & 15;
        int ki = ki_l[row];
        float4 v;
        if (ki < 0) { v.x = 0.f; v.y = 0.f; v.z = 0.f; v.w = 0.f; }
        else v = ((const float4*)(Vf + ((size_t)bh * LQ + ki) * DK))[c4];
        Vt[c4 * 4 + 0][row] = v.x; Vt[c4 * 4 + 1][row] = v.y;
        Vt[c4 * 4 + 2][row] = v.z; Vt[c4 * 4 + 3][row] = v.w;
    }
    float mrow[2][4], lsum[2][4];
#pragma unroll
    for (int mf = 0; mf < 2; ++mf)
#pragma unroll
        for (int reg = 0; reg < 4; ++reg) {
            int row = mf * 16 + gq * 4 + reg;
            float4 rm = *(const float4*)&redm[row][0];
            float m = fmaxf(fmaxf(rm.x, rm.y), fmaxf(rm.z, rm.w));
            mrow[mf][reg] = m;
            float e = expf(sv[mf][reg] - m);
            Pf[row][key] = e;
            float ps = e;
#pragma unroll
            for (int m_ = 1; m_ < 16; m_ <<= 1) ps += __shfl_xor(ps, m_);
            lsum[mf][reg] = ps;
        }
    if (la == 0) {
#pragma unroll
        for (int mf = 0; mf < 2; ++mf)
#pragma unroll
            for (int reg = 0; reg < 4; ++reg)
                redl[mf * 16 + gq * 4 + reg][wave] = lsum[mf][reg];
    }
    __syncthreads();
#pragma unroll
    for (int mf = 0; mf < 2; ++mf)
#pragma unroll
        for (int reg = 0; reg < 4; ++reg) {
            int row = mf * 16 + gq * 4 + reg;
            float4 rl = *(const float4*)&redl[row][0];
            lsum[mf][reg] = (rl.x + rl.y) + (rl.z + rl.w);
        }
    f32x4 accO[2] = {};
    {
        int dimr = wave * 16 + la;
        f16x8 bf2[2], af[2][2];
#pragma unroll
        for (int p = 0; p < 2; ++p) {
            const float* vsrc = &Vt[dimr][p * 32 + gq * 8];
            float4 b0 = *(const float4*)vsrc;
            float4 b1 = *(const float4*)(vsrc + 4);
            bf2[p] = pk8(b0, b1);
        }
#pragma unroll
        for (int mf = 0; mf < 2; ++mf) {
            int qrow = mf * 16 + la;
#pragma unroll
            for (int p = 0; p < 2; ++p) {
                const float* psrc = &Pf[qrow][p * 32 + gq * 8];
                float4 a0 = *(const float4*)psrc;
                float4 a1 = *(const float4*)(psrc + 4);
                af[mf][p] = pk8(a0, a1);
            }
        }
#pragma unroll
        for (int p = 0; p < 2; ++p)
#pragma unroll
            for (int mf = 0; mf < 2; ++mf)
                accO[mf] = __builtin_amdgcn_mfma_f32_16x16x32_f16(af[mf][p], bf2[p], accO[mf], 0, 0, 0);
    }
#pragma unroll
    for (int mf = 0; mf < 2; ++mf)
#pragma unroll
        for (int reg = 0; reg < 4; ++reg) {
            int row = mf * 16 + gq * 4 + reg;
            int srt = n * 32 + row;
            PV[(((size_t)pair * LQ + srt) << 6) + wave * 16 + la] = accO[mf][reg];
        }
    if (wave == 0 && la == 0) {
#pragma unroll
        for (int mf = 0; mf < 2; ++mf)
#pragma unroll
            for (int reg = 0; reg < 4; ++reg) {
                int row = mf * 16 + gq * 4 + reg;
                ML[(size_t)pair * LQ + n * 32 + row] = make_float2(mrow[mf][reg], lsum[mf][reg]);
            }
    }
}

// ---------------- K3: output projection, BK=64, double-buffered, fused combine (round-11) ----------------
__global__ __launch_bounds__(256) void out_combine(const float* __restrict__ PV,
                                                   const float2* __restrict__ ML,
                                                   const int* __restrict__ OIDX,
                                                   const ushort_t* __restrict__ WoTh,
                                                   const float* __restrict__ bo,
                                                   float* __restrict__ out) {
    __shared__ __align__(16) char SM[24576];
    const int tid = threadIdx.x;
    const int b = blockIdx.x;
    const int m0 = (b >> 3) * 32, n0 = (b & 7) * 64;
    const int wave = tid >> 6, lane = tid & 63;
    const int wm_ = wave & 1, wn_ = wave >> 1;
    const int la = lane & 15, gq = lane >> 4;
    const int arow = tid >> 3, aoct = tid & 7;
    const int abyte = arow * 128 + ((aoct ^ (arow & 7)) << 4);
    const int brow = tid >> 2, bslot = (tid & 3) * 2;
    const int bbyte0 = brow * 128 + ((bslot ^ (brow & 7)) << 4);
    const int bbyte1 = brow * 128 + (((bslot + 1) ^ (brow & 7)) << 4);
    const size_t gB = (size_t)(n0 + brow) * DD + bslot * 8;
    const int farow = wm_ * 16 + la;
    int fA[2], fB[2][2];
#pragma unroll
    for (int p2 = 0; p2 < 2; ++p2)
        fA[p2] = farow * 128 + (((p2 * 4 + gq) ^ (farow & 7)) << 4);
#pragma unroll
    for (int j = 0; j < 2; ++j) {
        int c = wn_ * 32 + j * 16 + la;
#pragma unroll
        for (int p2 = 0; p2 < 2; ++p2)
            fB[j][p2] = c * 128 + (((p2 * 4 + gq) ^ (c & 7)) << 4);
    }
    const int l = m0 + arow;
    float4 a00, a01, a10, a11; float2 ml0, ml1;
    auto FETCH = [&](int h) {
        size_t p0 = (size_t)h * RR, p1 = p0 + 1;
        int s0 = OIDX[p0 * LQ + l], s1 = OIDX[p1 * LQ + l];
        ml0 = ML[p0 * LQ + s0]; ml1 = ML[p1 * LQ + s1];
        const float* q0 = PV + ((p0 * LQ + s0) << 6) + aoct * 8;
        const float* q1 = PV + ((p1 * LQ + s1) << 6) + aoct * 8;
        a00 = ((const float4*)q0)[0]; a01 = ((const float4*)q0)[1];
        a10 = ((const float4*)q1)[0]; a11 = ((const float4*)q1)[1];
    };
    uint4 wh0 = *(const uint4*)(WoTh + gB);
    uint4 wh1 = *(const uint4*)(WoTh + gB + 8);
    FETCH(0);
    auto STAGE = [&](int pb) {
        char* base = SM + pb * 12288;
        float M = fmaxf(ml0.x, ml1.x);
        float w0 = expf(ml0.x - M);
        float w1 = expf(ml1.x - M);
        float denom = w0 * ml0.y + w1 * ml1.y;
        float4 c0, c1;
        c0.x = (w0 * a00.x + w1 * a10.x) / denom;
        c0.y = (w0 * a00.y + w1 * a10.y) / denom;
        c0.z = (w0 * a00.z + w1 * a10.z) / denom;
        c0.w = (w0 * a00.w + w1 * a10.w) / denom;
        c1.x = (w0 * a01.x + w1 * a11.x) / denom;
        c1.y = (w0 * a01.y + w1 * a11.y) / denom;
        c1.z = (w0 * a01.z + w1 * a11.z) / denom;
        c1.w = (w0 * a01.w + w1 * a11.w) / denom;
        *(uint4*)(base + abyte) = pku(c0, c1);
        *(uint4*)(base + 4096 + bbyte0) = wh0;
        *(uint4*)(base + 4096 + bbyte1) = wh1;
    };
    STAGE(0);
    f32x4 acc[2] = {};
    int p = 0;
    for (int kt = 0; kt < DD; kt += 64) {
        __syncthreads();
        const bool more = (kt + 64 < DD);
        if (more) {
            FETCH((kt + 64) >> 6);
            wh0 = *(const uint4*)(WoTh + gB + kt + 64);
            wh1 = *(const uint4*)(WoTh + gB + kt + 72);
        }
        char* base = SM + p * 12288;
#pragma unroll
        for (int p2 = 0; p2 < 2; ++p2) {
            f16x8 ah = *(const f16x8*)(base + fA[p2]);
            f16x8 bh0 = *(const f16x8*)(base + 4096 + fB[0][p2]);
            f16x8 bh1 = *(const f16x8*)(base + 4096 + fB[1][p2]);
            acc[0] = __builtin_amdgcn_mfma_f32_16x16x32_f16(ah, bh0, acc[0], 0, 0, 0);
            acc[1] = __builtin_amdgcn_mfma_f32_16x16x32_f16(ah, bh1, acc[1], 0, 0, 0);
        }
        if (more) STAGE(p ^ 1);
        p ^= 1;
    }
#pragma unroll
    for (int j = 0; j < 2; ++j) {
        int cl = wn_ * 32 + j * 16 + la;
        float bb_ = bo[n0 + cl];
#pragma unroll
        for (int reg = 0; reg < 4; ++reg) {
            int rl = wm_ * 16 + gq * 4 + reg;
            out[(size_t)(m0 + rl) * DD + n0 + cl] = acc[j][reg] + bb_;
        }
    }
}

extern "C" void kernel_launch(void* const* d_in, const int* in_sizes, int n_in,
                              void* d_out, int out_size, void* d_ws, size_t ws_size,
                              hipStream_t stream) {
    const float* query = (const float*)d_in[0];
    const float* value = (const float*)d_in[2];
    const float* Wq = (const float*)d_in[4];
    const float* bq = (const float*)d_in[5];
    const float* Wv = (const float*)d_in[6];
    const float* bv = (const float*)d_in[7];
    const float* Wo = (const float*)d_in[8];
    const float* bo = (const float*)d_in[9];
    const float* rnd = (const float*)d_in[10];

    char* ws = (char*)d_ws;
    const size_t MB1 = 1u << 20;
    const size_t HK = 512u << 10;
    float*    Qf    = (float*)(ws);                       // [0,2MB)
    float*    Vf    = (float*)(ws + 2 * MB1);             // [2,4MB)
    float*    PV    = (float*)(ws + 4 * MB1);             // [4,8MB)
    ushort_t* WqTh  = (ushort_t*)(ws + 8 * MB1);
    ushort_t* WqTm  = (ushort_t*)(ws + 8 * MB1 + HK);
    ushort_t* WvTh  = (ushort_t*)(ws + 9 * MB1);
    ushort_t* WoTh  = (ushort_t*)(ws + 9 * MB1 + HK);
    float*    RNORM = (float*)(ws + 10 * MB1);            // 32KB
    char*     tail  = ws + 10 * MB1 + (64u << 10);
    int* HASH  = (int*)(tail);
    int* OIDX  = (int*)(tail + (128u << 10));
    float2* ML = (float2*)(tail + (256u << 10));          // 128KB
    float* OUT = (float*)d_out;

    prep_w<<<768, 256, 0, stream>>>(Wq, Wv, Wo, WqTh, WqTm, WvTh, WoTh);
    gemm_hash<<<512, 256, 0, stream>>>(query, value, WqTh, WqTm, WvTh, bq, bv, rnd,
                                       Qf, Vf, HASH, RNORM);
    spv_sort<<<dim3(32, 2, 8), 256, 0, stream>>>(Qf, RNORM, Vf, HASH, OIDX, PV, ML);
    out_combine<<<256, 256, 0, stream>>>(PV, ML, OIDX, WoTh, bo, OUT);
}

// Round 14
// 61.435 us; speedup vs baseline: 1.0933x; 1.0735x over previous
//
#include <hip/hip_runtime.h>
#include <math.h>

#define LQ 1024
#define DD 512
#define DK 64
#define RR 2

typedef unsigned short ushort_t;
typedef __attribute__((ext_vector_type(8))) _Float16 f16x8;
typedef __attribute__((ext_vector_type(4))) float f32x4;

__device__ inline ushort_t f16b(float x) {
    union { _Float16 h; ushort_t u; } c; c.h = (_Float16)x; return c.u;
}
__device__ inline float f16tof(ushort_t u) {
    union { ushort_t u; _Float16 h; } c; c.u = u; return (float)c.h;
}
__device__ inline void store4u(ushort_t* p, const ushort_t h[4]) {
    uint2 v;
    v.x = h[0] | ((unsigned int)h[1] << 16); v.y = h[2] | ((unsigned int)h[3] << 16);
    *(uint2*)p = v;
}
__device__ inline uint4 pku(float4 a, float4 b) {
    uint4 v;
    v.x = (unsigned)f16b(a.x) | ((unsigned)f16b(a.y) << 16);
    v.y = (unsigned)f16b(a.z) | ((unsigned)f16b(a.w) << 16);
    v.z = (unsigned)f16b(b.x) | ((unsigned)f16b(b.y) << 16);
    v.w = (unsigned)f16b(b.z) | ((unsigned)f16b(b.w) << 16);
    return v;
}
__device__ inline f16x8 pk8(float4 a, float4 b) {
    f16x8 r;
    r[0] = (_Float16)a.x; r[1] = (_Float16)a.y; r[2] = (_Float16)a.z; r[3] = (_Float16)a.w;
    r[4] = (_Float16)b.x; r[5] = (_Float16)b.y; r[6] = (_Float16)b.z; r[7] = (_Float16)b.w;
    return r;
}

// ---------------- K0: weight transposes (Wq 2-level fp16, Wv/Wo 1-level fp16) ----------------
__global__ __launch_bounds__(256) void prep_w(const float* __restrict__ Wq,
                                              const float* __restrict__ Wv,
                                              const float* __restrict__ Wo,
                                              ushort_t* __restrict__ WqTh, ushort_t* __restrict__ WqTm,
                                              ushort_t* __restrict__ WvTh, ushort_t* __restrict__ WoTh) {
    __shared__ float tl[32][33];
    const int tid = threadIdx.x;
    const int b = blockIdx.x;
    const int mat = b >> 8;                // 0 Wq, 1 Wv, 2 Wo
    const int tile = b & 255;
    const int r0 = (tile >> 4) * 32;       // k rows
    const int c0 = (tile & 15) * 32;       // n cols
    const float* W = (mat == 0) ? Wq : ((mat == 1) ? Wv : Wo);
    const int rr = tid >> 3, cc = (tid & 7) * 4;
    *(float4*)&tl[rr][cc] = *(const float4*)(W + (size_t)(r0 + rr) * DD + c0 + cc);
    __syncthreads();
    float y[4];
#pragma unroll
    for (int i = 0; i < 4; ++i) y[i] = tl[cc + i][rr];
    size_t ob = (size_t)(c0 + rr) * DD + r0 + cc;
    if (mat == 0) {
        ushort_t h[4], m[4];
#pragma unroll
        for (int i = 0; i < 4; ++i) {
            h[i] = f16b(y[i]);
            m[i] = f16b((y[i] - f16tof(h[i])) * 2048.f);
        }
        store4u(WqTh + ob, h); store4u(WqTm + ob, m);
    } else {
        ushort_t h[4];
#pragma unroll
        for (int i = 0; i < 4; ++i) h[i] = f16b(y[i]);
        store4u((mat == 1 ? WvTh : WoTh) + ob, h);
    }
}

// ---------------- K1: projections + fused hash; BK=64, double-buffered LDS ----------------
__global__ __launch_bounds__(256) void gemm_hash(const float* __restrict__ query,
                                                 const float* __restrict__ value,
                                                 const ushort_t* __restrict__ WqTh,
                                                 const ushort_t* __restrict__ WqTm,
                                                 const ushort_t* __restrict__ WvTh,
                                                 const float* __restrict__ bq,
                                                 const float* __restrict__ bv,
                                                 const float* __restrict__ rnd,
                                                 float* __restrict__ Qf, float* __restrict__ Vf,
                                                 int* __restrict__ HASH, float* __restrict__ RNORM) {
    __shared__ __align__(16) char SM[49152];
    const int tid = threadIdx.x;
    const int b = blockIdx.x;
    const bool isQ = (b < 256);
    const int t = isQ ? b : b - 256;
    const int m0 = (t >> 3) * 32, n0 = (t & 7) * 64;
    const int wave = tid >> 6, lane = tid & 63;
    const int wm_ = wave & 1, wn_ = wave >> 1;
    const int la = lane & 15, gq = lane >> 4;
    const int arow = tid >> 3, aoct = tid & 7;
    const int abyte = arow * 128 + ((aoct ^ (arow & 7)) << 4);
    const int brow = tid >> 2, bslot = (tid & 3) * 2;
    const int bbyte0 = brow * 128 + ((bslot ^ (brow & 7)) << 4);
    const int bbyte1 = brow * 128 + (((bslot + 1) ^ (brow & 7)) << 4);
    const size_t gA = (size_t)(m0 + arow) * DD + aoct * 8;
    const size_t gB = (size_t)(n0 + brow) * DD + bslot * 8;
    const int farow = wm_ * 16 + la;
    int fA[2], fB[2][2];
#pragma unroll
    for (int p2 = 0; p2 < 2; ++p2)
        fA[p2] = farow * 128 + (((p2 * 4 + gq) ^ (farow & 7)) << 4);
#pragma unroll
    for (int j = 0; j < 2; ++j) {
        int c = wn_ * 32 + j * 16 + la;
#pragma unroll
        for (int p2 = 0; p2 < 2; ++p2)
            fB[j][p2] = c * 128 + (((p2 * 4 + gq) ^ (c & 7)) << 4);
    }
    const float* Asrc = isQ ? query : value;
    const ushort_t* Bh_src = isQ ? WqTh : WvTh;
    f32x4 acc0[2] = {}, acc1[2] = {};
    float4 xa0 = *(const float4*)(Asrc + gA);
    float4 xa1 = *(const float4*)(Asrc + gA + 4);
    uint4 wh0 = *(const uint4*)(Bh_src + gB);
    uint4 wh1 = *(const uint4*)(Bh_src + gB + 8);
    uint4 wm0 = {}, wm1 = {};
    if (isQ) { wm0 = *(const uint4*)(WqTm + gB); wm1 = *(const uint4*)(WqTm + gB + 8); }
    auto STAGE = [&](int pb) {
        char* base = SM + pb * 24576;
        *(uint4*)(base + abyte) = pku(xa0, xa1);
        if (isQ) {
            float4 r0, r1;
            r0.x = (xa0.x - f16tof(f16b(xa0.x))) * 2048.f;
            r0.y = (xa0.y - f16tof(f16b(xa0.y))) * 2048.f;
            r0.z = (xa0.z - f16tof(f16b(xa0.z))) * 2048.f;
            r0.w = (xa0.w - f16tof(f16b(xa0.w))) * 2048.f;
            r1.x = (xa1.x - f16tof(f16b(xa1.x))) * 2048.f;
            r1.y = (xa1.y - f16tof(f16b(xa1.y))) * 2048.f;
            r1.z = (xa1.z - f16tof(f16b(xa1.z))) * 2048.f;
            r1.w = (xa1.w - f16tof(f16b(xa1.w))) * 2048.f;
            *(uint4*)(base + 4096 + abyte) = pku(r0, r1);
        }
        *(uint4*)(base + 8192 + bbyte0) = wh0;
        *(uint4*)(base + 8192 + bbyte1) = wh1;
        if (isQ) {
            *(uint4*)(base + 16384 + bbyte0) = wm0;
            *(uint4*)(base + 16384 + bbyte1) = wm1;
        }
    };
    STAGE(0);
    int p = 0;
    for (int kt = 0; kt < DD; kt += 64) {
        __syncthreads();
        const bool more = (kt + 64 < DD);
        if (more) {
            xa0 = *(const float4*)(Asrc + gA + kt + 64);
            xa1 = *(const float4*)(Asrc + gA + kt + 68);
            wh0 = *(const uint4*)(Bh_src + gB + kt + 64);
            wh1 = *(const uint4*)(Bh_src + gB + kt + 72);
            if (isQ) {
                wm0 = *(const uint4*)(WqTm + gB + kt + 64);
                wm1 = *(const uint4*)(WqTm + gB + kt + 72);
            }
        }
        char* base = SM + p * 24576;
#pragma unroll
        for (int p2 = 0; p2 < 2; ++p2) {
            f16x8 ah = *(const f16x8*)(base + fA[p2]);
            f16x8 bh0 = *(const f16x8*)(base + 8192 + fB[0][p2]);
            f16x8 bh1 = *(const f16x8*)(base + 8192 + fB[1][p2]);
            acc0[0] = __builtin_amdgcn_mfma_f32_16x16x32_f16(ah, bh0, acc0[0], 0, 0, 0);
            acc0[1] = __builtin_amdgcn_mfma_f32_16x16x32_f16(ah, bh1, acc0[1], 0, 0, 0);
            if (isQ) {
                f16x8 am = *(const f16x8*)(base + 4096 + fA[p2]);
                f16x8 bm0 = *(const f16x8*)(base + 16384 + fB[0][p2]);
                f16x8 bm1 = *(const f16x8*)(base + 16384 + fB[1][p2]);
                acc1[0] = __builtin_amdgcn_mfma_f32_16x16x32_f16(ah, bm0, acc1[0], 0, 0, 0);
                acc1[0] = __builtin_amdgcn_mfma_f32_16x16x32_f16(am, bh0, acc1[0], 0, 0, 0);
                acc1[1] = __builtin_amdgcn_mfma_f32_16x16x32_f16(ah, bm1, acc1[1], 0, 0, 0);
                acc1[1] = __builtin_amdgcn_mfma_f32_16x16x32_f16(am, bh1, acc1[1], 0, 0, 0);
            }
        }
        if (more) STAGE(p ^ 1);
        p ^= 1;
    }
    __syncthreads();
    if (!isQ) {
#pragma unroll
        for (int j = 0; j < 2; ++j) {
            int cl = wn_ * 32 + j * 16 + la;
            float bias_ = bv[n0 + cl];
#pragma unroll
            for (int reg = 0; reg < 4; ++reg) {
                int rl = wm_ * 16 + gq * 4 + reg;
                Vf[(size_t)n0 * LQ + (size_t)(m0 + rl) * DK + cl] = acc0[j][reg] + bias_;
            }
        }
        return;
    }
    float (*qtile)[65] = (float(*)[65])SM;
    float (*rmn)[64] = (float(*)[64])(SM + 8320);
#pragma unroll
    for (int j = 0; j < 2; ++j) {
        int cl = wn_ * 32 + j * 16 + la;
        float bq_ = bq[n0 + cl];
#pragma unroll
        for (int reg = 0; reg < 4; ++reg) {
            int rl = wm_ * 16 + gq * 4 + reg;
            float x = acc0[j][reg] + acc1[j][reg] * (1.f / 2048.f) + bq_;
            Qf[(size_t)n0 * LQ + (size_t)(m0 + rl) * DK + cl] = x;
            qtile[rl][cl] = x;
        }
    }
    for (int idx = tid; idx < 4096; idx += 256)
        rmn[idx >> 6][idx & 63] = rnd[idx];
    __syncthreads();
    if (tid < 128) {
        int d = tid >> 1, rh = tid & 1;
        float s = 0.f;
        for (int j = 0; j < 32; ++j) { float x = rmn[d][rh * 32 + j]; s += x * x; }
        float nrm = sqrtf(s);
        for (int j = 0; j < 32; ++j) rmn[d][rh * 32 + j] = rmn[d][rh * 32 + j] / nrm;
    }
    __syncthreads();
    const int j = lane & 31, r = lane >> 5;
    const int bh = n0 >> 6;
    for (int it = 0; it < 8; ++it) {
        const int rl = it * 4 + wave;
        const int row = (bh << 10) + m0 + rl;
        float x = qtile[rl][lane];
        float s2 = x * x;
#pragma unroll
        for (int m = 1; m < 64; m <<= 1) s2 += __shfl_xor(s2, m);
        if (lane == 0) RNORM[row] = 1.0f / sqrtf(s2);
        float p0 = 0.f, p1 = 0.f, p2 = 0.f, p3 = 0.f;
#pragma unroll 4
        for (int d = 0; d < 64; d += 4) {
            p0 += __shfl(x, d + 0) * rmn[d + 0][lane];
            p1 += __shfl(x, d + 1) * rmn[d + 1][lane];
            p2 += __shfl(x, d + 2) * rmn[d + 2][lane];
            p3 += __shfl(x, d + 3) * rmn[d + 3][lane];
        }
        float pr = (p0 + p1) + (p2 + p3);
        float bv_; int bi;
        if (pr >= -pr) { bv_ = pr; bi = j; } else { bv_ = -pr; bi = 32 + j; }
#pragma unroll
        for (int m = 1; m < 32; m <<= 1) {
            float ov = __shfl_xor(bv_, m);
            int oi = __shfl_xor(bi, m);
            if (ov > bv_ || (ov == bv_ && oi < bi)) { bv_ = ov; bi = oi; }
        }
        if (j == 0) HASH[((size_t)bh * RR + r) * LQ + m0 + rl] = bi;
    }
}

// ---------------- K2: fused per-pair counting sort + scores + softmax + PV ----------------
__global__ __launch_bounds__(256) void spv_sort(const float* __restrict__ Q,
                                                const float* __restrict__ RNORM,
                                                const float* __restrict__ Vf,
                                                const int* __restrict__ HASH,
                                                int* __restrict__ OIDX,
                                                float* __restrict__ PV,
                                                float2* __restrict__ ML) {
    const int n = blockIdx.x, r = blockIdx.y, bh = blockIdx.z;
    const int pair = bh * RR + r;
    __shared__ __align__(16) char SM[45312];
    float (*Vt)[68] = (float(*)[68])SM;
    float (*Pf)[68] = (float(*)[68])(SM + 17408);
    float (*redm)[4] = (float(*)[4])(SM + 26112);
    float (*redl)[4] = (float(*)[4])(SM + 26624);
    int* qi_l = (int*)(SM + 27136);
    int* hsq  = (int*)(SM + 27264);
    int* Aq   = (int*)(SM + 27392);
    int* ki_l = (int*)(SM + 27520);
    int* hsk  = (int*)(SM + 27776);
    int* Ak   = (int*)(SM + 28032);
    float* krn  = (float*)(SM + 28288);
    float* lcnt = (float*)(SM + 28544);
    int* hl = (int*)SM;
    ushort_t (*cnt)[64] = (ushort_t(*)[64])(SM + 4096);
    int (*psum)[4] = (int(*)[4])(SM + 36864);
    int (*poff)[4] = (int(*)[4])(SM + 37888);
    int* sbase = (int*)(SM + 38912);
    ushort_t* HIl = (ushort_t*)(SM + 39168);
    ushort_t* HSl = (ushort_t*)(SM + 41216);
    ushort_t* OIl = (ushort_t*)(SM + 43264);
    const int tid = threadIdx.x;
    const int wave = tid >> 6, lane = tid & 63;
    const int la = lane & 15, gq = lane >> 4;
    {
        const int* hsrc = HASH + (size_t)pair * LQ;
        for (int i = tid; i < 1024; i += 256) hl[i] = hsrc[i];
        int* cz = (int*)(SM + 4096);
        for (int i = tid; i < 8192; i += 256) cz[i] = 0;
        __syncthreads();
        for (int i = 0; i < 4; ++i) {
            int h = hl[tid * 4 + i];
            cnt[tid][h] += 1;
        }
        __syncthreads();
        {
            int h = tid >> 2, seg = tid & 3;
            int run = 0;
            for (int tt = seg * 64; tt < seg * 64 + 64; ++tt) {
                int tmp = cnt[tt][h];
                cnt[tt][h] = (ushort_t)run;
                run += tmp;
            }
            psum[h][seg] = run;
        }
        __syncthreads();
        if (tid < 64) {
            int run = 0;
#pragma unroll
            for (int seg = 0; seg < 4; ++seg) { int t2 = psum[tid][seg]; poff[tid][seg] = run; run += t2; }
            int incl = run;
#pragma unroll
            for (int d = 1; d < 64; d <<= 1) {
                int y = __shfl_up(incl, d);
                if (tid >= d) incl += y;
            }
            sbase[tid] = incl - run;
        }
        __syncthreads();
        int* OIg = OIDX + (size_t)pair * LQ;
        const int myseg = tid >> 6;
        for (int i = 0; i < 4; ++i) {
            int l = tid * 4 + i;
            int h = hl[l];
            int pos = sbase[h] + poff[h][myseg] + cnt[tid][h];
            cnt[tid][h] = (ushort_t)(cnt[tid][h] + 1);
            HIl[pos] = (ushort_t)l;
            OIl[l] = (ushort_t)pos;
            HSl[pos] = (ushort_t)h;
            OIg[l] = pos;
        }
        __syncthreads();
    }
    if (tid < 32) {
        int s = n * 32 + tid;
        qi_l[tid] = HIl[s]; hsq[tid] = HSl[s]; Aq[tid] = OIl[s];
    } else if (tid < 96) {
        int k = tid - 32;
        int t2 = (n - 1) * 32 + k;
        if (t2 < 0) { ki_l[k] = -1; hsk[k] = 0; Ak[k] = 0; krn[k] = 0.f; }
        else {
            int ki = HIl[t2];
            ki_l[k] = ki; hsk[k] = HSl[t2]; Ak[k] = OIl[t2];
            krn[k] = RNORM[(size_t)bh * LQ + ki];
        }
    }
    __syncthreads();
    if (tid == 0) {
        if (n > 0) {
            for (int k = 0; k < 64; ++k) lcnt[k] = 0.f;
        } else {
            int zc = 0;
            for (int k = 32; k < 64; ++k) zc += (Ak[k] == 0);
            float l32 = logf((float)(32 + zc));
            for (int k = 0; k < 32; ++k) lcnt[k] = l32;
            for (int k = 32; k < 64; ++k) lcnt[k] = (Ak[k] == 0) ? l32 : 0.f;
        }
    }
    {
        int row = tid >> 3, o = tid & 7;
        const float* src = Q + ((size_t)bh * LQ + qi_l[row]) * DK + o * 8;
        float4 u0 = ((const float4*)src)[0];
        float4 u1 = ((const float4*)src)[1];
        int p = o >> 2, s = o & 3;
        int sw = (row & 3) ^ ((row >> 2) & 3);
        *(uint4*)(SM + p * 2048 + row * 64 + ((s ^ sw) << 4)) = pku(u0, u1);
    }
    {
        int row = tid >> 2, o2 = tid & 3;
        int ki = ki_l[row];
        float rn = krn[row];
        float4 u0 = {0,0,0,0}, u1 = {0,0,0,0}, u2 = {0,0,0,0}, u3 = {0,0,0,0};
        if (ki >= 0) {
            const float* src = Q + ((size_t)bh * LQ + ki) * DK + o2 * 16;
            u0 = ((const float4*)src)[0]; u1 = ((const float4*)src)[1];
            u2 = ((const float4*)src)[2]; u3 = ((const float4*)src)[3];
            u0.x *= rn; u0.y *= rn; u0.z *= rn; u0.w *= rn;
            u1.x *= rn; u1.y *= rn; u1.z *= rn; u1.w *= rn;
            u2.x *= rn; u2.y *= rn; u2.z *= rn; u2.w *= rn;
            u3.x *= rn; u3.y *= rn; u3.z *= rn; u3.w *= rn;
        }
        int p = o2 >> 1, sb = (o2 & 1) * 2;
        int sw = (row & 3) ^ ((row >> 2) & 3);
        *(uint4*)(SM + 4096 + p * 4096 + row * 64 + ((sb ^ sw) << 4)) = pku(u0, u1);
        *(uint4*)(SM + 4096 + p * 4096 + row * 64 + (((sb + 1) ^ sw) << 4)) = pku(u2, u3);
    }
    __syncthreads();
    f32x4 accS[2] = {};
    {
        int rb = wave * 16 + la;
        int swb = (rb & 3) ^ ((rb >> 2) & 3);
        f16x8 bk[2], aq[2][2];
#pragma unroll
        for (int p = 0; p < 2; ++p)
            bk[p] = *(const f16x8*)(SM + 4096 + p * 4096 + rb * 64 + (((gq) ^ swb) << 4));
#pragma unroll
        for (int mf = 0; mf < 2; ++mf) {
            int ra = mf * 16 + la;
            int swa = (ra & 3) ^ ((ra >> 2) & 3);
#pragma unroll
            for (int p = 0; p < 2; ++p)
                aq[mf][p] = *(const f16x8*)(SM + p * 2048 + ra * 64 + (((gq) ^ swa) << 4));
        }
#pragma unroll
        for (int p = 0; p < 2; ++p)
#pragma unroll
            for (int mf = 0; mf < 2; ++mf)
                accS[mf] = __builtin_amdgcn_mfma_f32_16x16x32_f16(aq[mf][p], bk[p], accS[mf], 0, 0, 0);
    }
    const int key = wave * 16 + la;
    const int hk = hsk[key], ak = Ak[key];
    const float lc = lcnt[key];
    float sv[2][4], pmax[2][4];
#pragma unroll
    for (int mf = 0; mf < 2; ++mf)
#pragma unroll
        for (int reg = 0; reg < 4; ++reg) {
            int row = mf * 16 + gq * 4 + reg;
            int hq = hsq[row], aqv = Aq[row];
            float v = accS[mf][reg] * 0.125f;
            v = v - ((n == 0 && wave < 2) ? 1e9f : 0.f);
            v = v - ((hq == hk) ? 0.f : 1e9f);
            v = v - ((aqv > ak) ? 0.f : 1e9f);
            v = v - ((aqv == ak) ? 1e5f : 0.f);
            v = v - lc;
            sv[mf][reg] = v;
            float pm = v;
#pragma unroll
            for (int m_ = 1; m_ < 16; m_ <<= 1) pm = fmaxf(pm, __shfl_xor(pm, m_));
            pmax[mf][reg] = pm;
        }
    if (la == 0) {
#pragma unroll
        for (int mf = 0; mf < 2; ++mf)
#pragma unroll
            for (int reg = 0; reg < 4; ++reg)
                redm[mf * 16 + gq * 4 + reg][wave] = pmax[mf][reg];
    }
    __syncthreads();
    for (int idx = tid; idx < 64 * 16; idx += 256) {
        int row = idx >> 4, c4 = idx & 15;
        int ki = ki_l[row];
        float4 v;
        if (ki < 0) { v.x = 0.f; v.y = 0.f; v.z = 0.f; v.w = 0.f; }
        else v = ((const float4*)(Vf + ((size_t)bh * LQ + ki) * DK))[c4];
        Vt[c4 * 4 + 0][row] = v.x; Vt[c4 * 4 + 1][row] = v.y;
        Vt[c4 * 4 + 2][row] = v.z; Vt[c4 * 4 + 3][row] = v.w;
    }
    float mrow[2][4], lsum[2][4];
#pragma unroll
    for (int mf = 0; mf < 2; ++mf)
#pragma unroll
        for (int reg = 0; reg < 4; ++reg) {
            int row = mf * 16 + gq * 4 + reg;
            float4 rm = *(const float4*)&redm[row][0];
            float m = fmaxf(fmaxf(rm.x, rm.y), fmaxf(rm.z, rm.w));
            mrow[mf][reg] = m;
            float e = expf(sv[mf][reg] - m);
            Pf[row][key] = e;
            float ps = e;
#pragma unroll
            for (int m_ = 1; m_ < 16; m_ <<= 1) ps += __shfl_xor(ps, m_);
            lsum[mf][reg] = ps;
        }
    if (la == 0) {
#pragma unroll
        for (int mf = 0; mf < 2; ++mf)
#pragma unroll
            for (int reg = 0; reg < 4; ++reg)
                redl[mf * 16 + gq * 4 + reg][wave] = lsum[mf][reg];
    }
    __syncthreads();
#pragma unroll
    for (int mf = 0; mf < 2; ++mf)
#pragma unroll
        for (int reg = 0; reg < 4; ++reg) {
            int row = mf * 16 + gq * 4 + reg;
            float4 rl = *(const float4*)&redl[row][0];
            lsum[mf][reg] = (rl.x + rl.y) + (rl.z + rl.w);
        }
    f32x4 accO[2] = {};
    {
        int dimr = wave * 16 + la;
        f16x8 bf2[2], af[2][2];
#pragma unroll
        for (int p = 0; p < 2; ++p) {
            const float* vsrc = &Vt[dimr][p * 32 + gq * 8];
            float4 b0 = *(const float4*)vsrc;
            float4 b1 = *(const float4*)(vsrc + 4);
            bf2[p] = pk8(b0, b1);
        }
#pragma unroll
        for (int mf = 0; mf < 2; ++mf) {
            int qrow = mf * 16 + la;
#pragma unroll
            for (int p = 0; p < 2; ++p) {
                const float* psrc = &Pf[qrow][p * 32 + gq * 8];
                float4 a0 = *(const float4*)psrc;
                float4 a1 = *(const float4*)(psrc + 4);
                af[mf][p] = pk8(a0, a1);
            }
        }
#pragma unroll
        for (int p = 0; p < 2; ++p)
#pragma unroll
            for (int mf = 0; mf < 2; ++mf)
                accO[mf] = __builtin_amdgcn_mfma_f32_16x16x32_f16(af[mf][p], bf2[p], accO[mf], 0, 0, 0);
    }
#pragma unroll
    for (int mf = 0; mf < 2; ++mf)
#pragma unroll
        for (int reg = 0; reg < 4; ++reg) {
            int row = mf * 16 + gq * 4 + reg;
            int srt = n * 32 + row;
            PV[(((size_t)pair * LQ + srt) << 6) + wave * 16 + la] = accO[mf][reg];
        }
    if (wave == 0 && la == 0) {
#pragma unroll
        for (int mf = 0; mf < 2; ++mf)
#pragma unroll
            for (int reg = 0; reg < 4; ++reg) {
                int row = mf * 16 + gq * 4 + reg;
                ML[(size_t)pair * LQ + n * 32 + row] = make_float2(mrow[mf][reg], lsum[mf][reg]);
            }
    }
}

// ---------------- K3: output projection v2 — 512 blocks (16x64), hoisted combine meta ----------------
__global__ __launch_bounds__(256) void out_combine(const float* __restrict__ PV,
                                                   const float2* __restrict__ ML,
                                                   const int* __restrict__ OIDX,
                                                   const ushort_t* __restrict__ WoTh,
                                                   const float* __restrict__ bo,
                                                   float* __restrict__ out) {
    // per buffer (stride 12288): Ah@0 (2KB), Bh@2048 (8KB); 2 buffers
    __shared__ __align__(16) char SM[24576];
    const int tid = threadIdx.x;
    const int b = blockIdx.x;
    const int m0 = (b >> 3) * 16, n0 = (b & 7) * 64;
    const int wave = tid >> 6, lane = tid & 63;
    const int la = lane & 15, gq = lane >> 4;
    // A staging: thread -> (row = tid>>4, quad q4 = tid&15), 4 fp16 (uint2)
    const int arow = tid >> 4, q4 = tid & 15;
    const int au = q4 >> 1, ahalf = q4 & 1;
    const int abyte = arow * 128 + ((au ^ (arow & 7)) << 4) + ahalf * 8;
    const int d0 = q4 * 4;                 // dim offset within head
    // B staging (identical layout to round 13)
    const int brow = tid >> 2, bslot = (tid & 3) * 2;
    const int bbyte0 = brow * 128 + ((bslot ^ (brow & 7)) << 4);
    const int bbyte1 = brow * 128 + (((bslot + 1) ^ (brow & 7)) << 4);
    const size_t gB = (size_t)(n0 + brow) * DD + bslot * 8;
    // fragment offsets
    int fA[2], fB[2];
#pragma unroll
    for (int p2 = 0; p2 < 2; ++p2)
        fA[p2] = la * 128 + (((p2 * 4 + gq) ^ (la & 7)) << 4);
    {
        int c = wave * 16 + la;
#pragma unroll
        for (int p2 = 0; p2 < 2; ++p2)
            fB[p2] = c * 128 + (((p2 * 4 + gq) ^ (c & 7)) << 4);
    }
    const int l = m0 + arow;
    // prologue: hoist per-head gather meta + combine weights (identical expressions)
    int s0a[8], s1a[8]; float w0a[8], w1a[8], dna[8];
#pragma unroll
    for (int h = 0; h < 8; ++h) {
        int s0 = OIDX[(size_t)(2 * h) * LQ + l];
        int s1 = OIDX[(size_t)(2 * h + 1) * LQ + l];
        float2 ml0 = ML[(size_t)(2 * h) * LQ + s0];
        float2 ml1 = ML[(size_t)(2 * h + 1) * LQ + s1];
        float M = fmaxf(ml0.x, ml1.x);
        float w0 = expf(ml0.x - M);
        float w1 = expf(ml1.x - M);
        s0a[h] = s0; s1a[h] = s1; w0a[h] = w0; w1a[h] = w1;
        dna[h] = w0 * ml0.y + w1 * ml1.y;
    }
    float4 a0 = *(const float4*)(PV + (((size_t)0 * LQ + s0a[0]) << 6) + d0);
    float4 a1 = *(const float4*)(PV + (((size_t)1 * LQ + s1a[0]) << 6) + d0);
    uint4 wh0 = *(const uint4*)(WoTh + gB);
    uint4 wh1 = *(const uint4*)(WoTh + gB + 8);
    auto STAGE = [&](int pb, int hh) {
        char* base = SM + pb * 12288;
        float w0 = w0a[hh], w1 = w1a[hh], dn = dna[hh];
        float4 c0;
        c0.x = (w0 * a0.x + w1 * a1.x) / dn;
        c0.y = (w0 * a0.y + w1 * a1.y) / dn;
        c0.z = (w0 * a0.z + w1 * a1.z) / dn;
        c0.w = (w0 * a0.w + w1 * a1.w) / dn;
        uint2 hv;
        hv.x = (unsigned)f16b(c0.x) | ((unsigned)f16b(c0.y) << 16);
        hv.y = (unsigned)f16b(c0.z) | ((unsigned)f16b(c0.w) << 16);
        *(uint2*)(base + abyte) = hv;
        *(uint4*)(base + 2048 + bbyte0) = wh0;
        *(uint4*)(base + 2048 + bbyte1) = wh1;
    };
    STAGE(0, 0);
    f32x4 acc = {};
    int p = 0;
#pragma unroll
    for (int h = 0; h < 8; ++h) {
        __syncthreads();
        if (h < 7) {
            a0 = *(const float4*)(PV + (((size_t)(2 * (h + 1)) * LQ + s0a[h + 1]) << 6) + d0);
            a1 = *(const float4*)(PV + (((size_t)(2 * (h + 1) + 1) * LQ + s1a[h + 1]) << 6) + d0);
            wh0 = *(const uint4*)(WoTh + gB + (h + 1) * 64);
            wh1 = *(const uint4*)(WoTh + gB + (h + 1) * 64 + 8);
        }
        char* base = SM + p * 12288;
#pragma unroll
        for (int p2 = 0; p2 < 2; ++p2) {
            f16x8 ah = *(const f16x8*)(base + fA[p2]);
            f16x8 bh = *(const f16x8*)(base + 2048 + fB[p2]);
            acc = __builtin_amdgcn_mfma_f32_16x16x32_f16(ah, bh, acc, 0, 0, 0);
        }
        if (h < 7) STAGE(p ^ 1, h + 1);
        p ^= 1;
    }
    {
        int cl = wave * 16 + la;
        float bb_ = bo[n0 + cl];
#pragma unroll
        for (int reg = 0; reg < 4; ++reg) {
            int rl = gq * 4 + reg;
            out[(size_t)(m0 + rl) * DD + n0 + cl] = acc[reg] + bb_;
        }
    }
}

extern "C" void kernel_launch(void* const* d_in, const int* in_sizes, int n_in,
                              void* d_out, int out_size, void* d_ws, size_t ws_size,
                              hipStream_t stream) {
    const float* query = (const float*)d_in[0];
    const float* value = (const float*)d_in[2];
    const float* Wq = (const float*)d_in[4];
    const float* bq = (const float*)d_in[5];
    const float* Wv = (const float*)d_in[6];
    const float* bv = (const float*)d_in[7];
    const float* Wo = (const float*)d_in[8];
    const float* bo = (const float*)d_in[9];
    const float* rnd = (const float*)d_in[10];

    char* ws = (char*)d_ws;
    const size_t MB1 = 1u << 20;
    const size_t HK = 512u << 10;
    float*    Qf    = (float*)(ws);                       // [0,2MB)
    float*    Vf    = (float*)(ws + 2 * MB1);             // [2,4MB)
    float*    PV    = (float*)(ws + 4 * MB1);             // [4,8MB)
    ushort_t* WqTh  = (ushort_t*)(ws + 8 * MB1);
    ushort_t* WqTm  = (ushort_t*)(ws + 8 * MB1 + HK);
    ushort_t* WvTh  = (ushort_t*)(ws + 9 * MB1);
    ushort_t* WoTh  = (ushort_t*)(ws + 9 * MB1 + HK);
    float*    RNORM = (float*)(ws + 10 * MB1);            // 32KB
    char*     tail  = ws + 10 * MB1 + (64u << 10);
    int* HASH  = (int*)(tail);
    int* OIDX  = (int*)(tail + (128u << 10));
    float2* ML = (float2*)(tail + (256u << 10));          // 128KB
    float* OUT = (float*)d_out;

    prep_w<<<768, 256, 0, stream>>>(Wq, Wv, Wo, WqTh, WqTm, WvTh, WoTh);
    gemm_hash<<<512, 256, 0, stream>>>(query, value, WqTh, WqTm, WvTh, bq, bv, rnd,
                                       Qf, Vf, HASH, RNORM);
    spv_sort<<<dim3(32, 2, 8), 256, 0, stream>>>(Qf, RNORM, Vf, HASH, OIDX, PV, ML);
    out_combine<<<512, 256, 0, stream>>>(PV, ML, OIDX, WoTh, bo, OUT);
}